// Round 2
// baseline (2788.359 us; speedup 1.0000x reference)
//
#include <hip/hip_runtime.h>
#include <hip/hip_bf16.h>

// Problem constants (from reference): B=2, S=2048, E=1024, H=16, P=2048, HD=64
#define BB 2
#define SS 2048
#define EE 1024
#define HH 16
#define PP 2048
#define HDIM 64
#define SCALE 0.125f   // HD^-0.5

// ---------------------------------------------------------------------------
// GEMM: C[M,N] = A[M,K] @ W[K,N] + bias[N]   (fp32, row-major everywhere)
// BM=128, BN=128, BK=16, 256 threads, 8x8 micro-tile.
// ---------------------------------------------------------------------------
#define GBM 128
#define GBN 128
#define GBK 16

__global__ __launch_bounds__(256) void gemm_bias_kernel(
    const float* __restrict__ A, const float* __restrict__ W,
    const float* __restrict__ bias, float* __restrict__ C,
    int M, int N, int K) {
  __shared__ float As[GBK][GBM + 4];
  __shared__ float Bs[GBK][GBN + 4];

  const int tid = threadIdx.x;
  const int bm = blockIdx.y * GBM;
  const int bn = blockIdx.x * GBN;

  const int tr = tid >> 4;        // 0..15 row group
  const int tc = tid & 15;        // 0..15 col group

  // A staging: thread loads 2 rows (ar, ar+64), 4 consecutive cols
  const int ar = tid >> 2;            // 0..63
  const int ac = (tid & 3) * 4;       // 0,4,8,12
  // B staging: thread loads 2 rows (br, br+8), 4 consecutive cols
  const int br = tid >> 5;            // 0..7
  const int bc = (tid & 31) * 4;      // 0..124

  float acc[8][8];
#pragma unroll
  for (int i = 0; i < 8; i++)
#pragma unroll
    for (int j = 0; j < 8; j++) acc[i][j] = 0.f;

  for (int k0 = 0; k0 < K; k0 += GBK) {
#pragma unroll
    for (int i = 0; i < 2; i++) {
      const int m = ar + i * 64;
      const float4 va = *(const float4*)&A[(size_t)(bm + m) * K + k0 + ac];
      As[ac + 0][m] = va.x;
      As[ac + 1][m] = va.y;
      As[ac + 2][m] = va.z;
      As[ac + 3][m] = va.w;
    }
#pragma unroll
    for (int i = 0; i < 2; i++) {
      const int kk = br + i * 8;
      *(float4*)&Bs[kk][bc] = *(const float4*)&W[(size_t)(k0 + kk) * N + bn + bc];
    }
    __syncthreads();

#pragma unroll
    for (int kk = 0; kk < GBK; kk++) {
      float a[8], b[8];
      *(float4*)&a[0] = *(const float4*)&As[kk][tr * 8];
      *(float4*)&a[4] = *(const float4*)&As[kk][tr * 8 + 4];
      *(float4*)&b[0] = *(const float4*)&Bs[kk][tc * 8];
      *(float4*)&b[4] = *(const float4*)&Bs[kk][tc * 8 + 4];
#pragma unroll
      for (int i = 0; i < 8; i++)
#pragma unroll
        for (int j = 0; j < 8; j++) acc[i][j] = fmaf(a[i], b[j], acc[i][j]);
    }
    __syncthreads();
  }

#pragma unroll
  for (int i = 0; i < 8; i++) {
    const int m = bm + tr * 8 + i;
#pragma unroll
    for (int j = 0; j < 8; j += 4) {
      const int n = bn + tc * 8 + j;
      float4 o;
      o.x = acc[i][j + 0] + bias[n + 0];
      o.y = acc[i][j + 1] + bias[n + 1];
      o.z = acc[i][j + 2] + bias[n + 2];
      o.w = acc[i][j + 3] + bias[n + 3];
      *(float4*)&C[(size_t)m * N + n] = o;
    }
  }
}

// ---------------------------------------------------------------------------
// Flash attention with fused relative-position bias.
// score(i,j) = scale * ( q_i . k_j + q_i . rel_key[j-i+P-1] )
//            = scale * ( q_i . (k_j + rel_row) )
// One block (256 thr) per (b, h, 64-query tile). Layout of q/k/v buffers is
// [B, S, E] with head h occupying cols [h*64, h*64+64).
// Thread map: r = tid>>2 (query row 0..63), c = tid&3 (j-quarter / dim-quarter)
// ---------------------------------------------------------------------------
__global__ __launch_bounds__(256) void attn_kernel(
    const float* __restrict__ q, const float* __restrict__ k,
    const float* __restrict__ v, const float* __restrict__ rel,
    float* __restrict__ att) {
  __shared__ float Ks[64][68];   // reused as P-buffer after score phase
  __shared__ float Vs[64][68];
  __shared__ float Rs[128][68];

  const int b = blockIdx.z;
  const int h = blockIdx.y;
  const int i0 = blockIdx.x * 64;
  const int tid = threadIdx.x;
  const int r = tid >> 2;        // query row in tile
  const int c = tid & 3;         // quarter
  const int qi = i0 + r;         // global query index
  const size_t hoff = (size_t)h * HDIM;

  // Q row into registers (4-lane redundant, once per block — cheap)
  float qreg[64];
  {
    const float* qrow = q + ((size_t)(b * SS + qi)) * EE + hoff;
#pragma unroll
    for (int d4 = 0; d4 < 16; d4++)
      *(float4*)&qreg[d4 * 4] = *(const float4*)&qrow[d4 * 4];
  }

  float acc[16];
#pragma unroll
  for (int d = 0; d < 16; d++) acc[d] = 0.f;
  float m_run = -1e30f, l_run = 0.f;

  const int lr = tid >> 2;           // staging row 0..63
  const int lc = (tid & 3) * 16;     // staging col 0/16/32/48

  const int nkt = i0 / 64 + 1;       // causal: key tiles 0..i0/64
  for (int kt = 0; kt < nkt; kt++) {
    const int j0 = kt * 64;

    // ---- stage K, V tiles ----
    {
      const float* kb = k + ((size_t)(b * SS + j0 + lr)) * EE + hoff + lc;
      const float* vb = v + ((size_t)(b * SS + j0 + lr)) * EE + hoff + lc;
#pragma unroll
      for (int i = 0; i < 4; i++) {
        *(float4*)&Ks[lr][lc + i * 4] = *(const float4*)&kb[i * 4];
        *(float4*)&Vs[lr][lc + i * 4] = *(const float4*)&vb[i * 4];
      }
    }
    // ---- stage rel_key slice: rows base..base+127 (clamped) ----
    {
      const int base = j0 - i0 + PP - 64;   // >= 0 always for causal tiles
#pragma unroll
      for (int half = 0; half < 2; half++) {
        const int lrow = lr + half * 64;
        int rowg = base + lrow;
        if (rowg > PP - 1) rowg = PP - 1;   // rows past P-1 are masked anyway
        const float* rb = rel + (size_t)rowg * HDIM + lc;
#pragma unroll
        for (int i = 0; i < 4; i++)
          *(float4*)&Rs[lrow][lc + i * 4] = *(const float4*)&rb[i * 4];
      }
    }
    __syncthreads();

    // ---- scores: 16 j's per thread ----
    float p[16];
    float mloc = -1e30f;
#pragma unroll
    for (int jj = 0; jj < 16; jj++) {
      const int jl = c * 16 + jj;            // local key idx 0..63
      const int relrow = jl - r + 63;        // 0..126
      float s = 0.f;
#pragma unroll
      for (int d = 0; d < 64; d += 4) {
        const float4 kv = *(const float4*)&Ks[jl][d];
        const float4 rv = *(const float4*)&Rs[relrow][d];
        s = fmaf(qreg[d + 0], kv.x + rv.x, s);
        s = fmaf(qreg[d + 1], kv.y + rv.y, s);
        s = fmaf(qreg[d + 2], kv.z + rv.z, s);
        s = fmaf(qreg[d + 3], kv.w + rv.w, s);
      }
      s *= SCALE;
      if (j0 + jl > qi) s = -1e30f;          // causal mask
      p[jj] = s;
      mloc = fmaxf(mloc, s);
    }
    // row max across the 4 lanes of this row
    mloc = fmaxf(mloc, __shfl_xor(mloc, 1));
    mloc = fmaxf(mloc, __shfl_xor(mloc, 2));
    const float m_new = fmaxf(m_run, mloc);
    const float corr = __expf(m_run - m_new);
    float lsum = 0.f;
#pragma unroll
    for (int jj = 0; jj < 16; jj++) {
      const float e = __expf(p[jj] - m_new);
      p[jj] = e;
      lsum += e;
    }
    lsum += __shfl_xor(lsum, 1);
    lsum += __shfl_xor(lsum, 2);
    l_run = l_run * corr + lsum;
    m_run = m_new;
#pragma unroll
    for (int d = 0; d < 16; d++) acc[d] *= corr;

    __syncthreads();   // all score-phase reads of Ks done → safe to alias
    float* Ps = &Ks[0][0];
#pragma unroll
    for (int i = 0; i < 4; i++)
      *(float4*)&Ps[r * 68 + c * 16 + i * 4] = *(const float4*)&p[i * 4];
    __syncthreads();

    // ---- PV: acc[d] += sum_j p[j] * V[j][c*16+d] ----
    for (int jl = 0; jl < 64; jl++) {
      const float pv = Ps[r * 68 + jl];
      const float4 v0 = *(const float4*)&Vs[jl][c * 16 + 0];
      const float4 v1 = *(const float4*)&Vs[jl][c * 16 + 4];
      const float4 v2 = *(const float4*)&Vs[jl][c * 16 + 8];
      const float4 v3 = *(const float4*)&Vs[jl][c * 16 + 12];
      acc[0] = fmaf(pv, v0.x, acc[0]);
      acc[1] = fmaf(pv, v0.y, acc[1]);
      acc[2] = fmaf(pv, v0.z, acc[2]);
      acc[3] = fmaf(pv, v0.w, acc[3]);
      acc[4] = fmaf(pv, v1.x, acc[4]);
      acc[5] = fmaf(pv, v1.y, acc[5]);
      acc[6] = fmaf(pv, v1.z, acc[6]);
      acc[7] = fmaf(pv, v1.w, acc[7]);
      acc[8] = fmaf(pv, v2.x, acc[8]);
      acc[9] = fmaf(pv, v2.y, acc[9]);
      acc[10] = fmaf(pv, v2.z, acc[10]);
      acc[11] = fmaf(pv, v2.w, acc[11]);
      acc[12] = fmaf(pv, v3.x, acc[12]);
      acc[13] = fmaf(pv, v3.y, acc[13]);
      acc[14] = fmaf(pv, v3.z, acc[14]);
      acc[15] = fmaf(pv, v3.w, acc[15]);
    }
    __syncthreads();   // protect Ks/Vs/Rs before next tile's stores
  }

  // ---- epilogue: normalize and store ----
  const float inv_l = 1.f / l_run;
  float* orow = att + ((size_t)(b * SS + qi)) * EE + hoff + c * 16;
#pragma unroll
  for (int i = 0; i < 4; i++) {
    float4 o;
    o.x = acc[i * 4 + 0] * inv_l;
    o.y = acc[i * 4 + 1] * inv_l;
    o.z = acc[i * 4 + 2] * inv_l;
    o.w = acc[i * 4 + 3] * inv_l;
    *(float4*)&orow[i * 4] = o;
  }
}

// ---------------------------------------------------------------------------
// Launch
// ---------------------------------------------------------------------------
extern "C" void kernel_launch(void* const* d_in, const int* in_sizes, int n_in,
                              void* d_out, int out_size, void* d_ws, size_t ws_size,
                              hipStream_t stream) {
  const float* x   = (const float*)d_in[0];
  const float* Wq  = (const float*)d_in[1];
  const float* bq  = (const float*)d_in[2];
  const float* Wk  = (const float*)d_in[3];
  const float* bk  = (const float*)d_in[4];
  const float* Wv  = (const float*)d_in[5];
  const float* bv  = (const float*)d_in[6];
  const float* Wo  = (const float*)d_in[7];
  const float* bo  = (const float*)d_in[8];
  const float* rel = (const float*)d_in[9];
  float* out = (float*)d_out;

  const int M = BB * SS;   // 4096
  const int N = EE;        // 1024
  const int K = EE;        // 1024

  const size_t buf = (size_t)M * EE;   // 4.19M floats each
  float* qb = (float*)d_ws;
  float* kb = qb + buf;
  float* vb = kb + buf;
  float* ab = vb + buf;

  dim3 gemm_grid(N / GBN, M / GBM);   // (8, 32)
  dim3 gemm_blk(256);

  hipLaunchKernelGGL(gemm_bias_kernel, gemm_grid, gemm_blk, 0, stream,
                     x, Wq, bq, qb, M, N, K);
  hipLaunchKernelGGL(gemm_bias_kernel, gemm_grid, gemm_blk, 0, stream,
                     x, Wk, bk, kb, M, N, K);
  hipLaunchKernelGGL(gemm_bias_kernel, gemm_grid, gemm_blk, 0, stream,
                     x, Wv, bv, vb, M, N, K);

  dim3 attn_grid(SS / 64, HH, BB);    // (32, 16, 2)
  hipLaunchKernelGGL(attn_kernel, attn_grid, dim3(256), 0, stream,
                     qb, kb, vb, rel, ab);

  hipLaunchKernelGGL(gemm_bias_kernel, gemm_grid, gemm_blk, 0, stream,
                     ab, Wo, bo, out, M, N, K);
}

// Round 3
// 878.608 us; speedup vs baseline: 3.1736x; 3.1736x over previous
//
#include <hip/hip_runtime.h>
#include <hip/hip_bf16.h>

// Problem constants: B=2, S=2048, E=1024, H=16, P=2048, HD=64
#define BB 2
#define SS 2048
#define EE 1024
#define HH 16
#define PP 2048
#define HDIM 64
#define SCALE 0.125f

typedef short bf16x8 __attribute__((ext_vector_type(8)));
typedef float f32x4 __attribute__((ext_vector_type(4)));
typedef unsigned short u16x8 __attribute__((ext_vector_type(8)));

#define MFMA16(a, b, c) __builtin_amdgcn_mfma_f32_16x16x32_bf16(a, b, c, 0, 0, 0)

__device__ __forceinline__ unsigned short f2bf(float f) {
  unsigned int u = __float_as_uint(f);
  unsigned int r = (u + 0x7FFFu + ((u >> 16) & 1u)) >> 16;
  return (unsigned short)r;
}
__device__ __forceinline__ float bf2f(unsigned short h) {
  return __uint_as_float((unsigned int)h << 16);
}

// swizzled 16B-chunk offset (ushort units) within a [64 rows][64 bf16] tile
#define KOFF(row, chunk) (((row) << 6) + ((((chunk) ^ ((row) & 7))) << 3))

// ---------------------------------------------------------------------------
// fp32 GEMM + bias (for the output projection)
// ---------------------------------------------------------------------------
#define GBM 128
#define GBN 128
#define GBK 16

__global__ __launch_bounds__(256) void gemm_bias_kernel(
    const float* __restrict__ A, const float* __restrict__ W,
    const float* __restrict__ bias, float* __restrict__ C,
    int M, int N, int K) {
  __shared__ float As[GBK][GBM + 4];
  __shared__ float Bs[GBK][GBN + 4];
  const int tid = threadIdx.x;
  const int bm = blockIdx.y * GBM, bn = blockIdx.x * GBN;
  const int tr = tid >> 4, tc = tid & 15;
  const int ar = tid >> 2, ac = (tid & 3) * 4;
  const int br = tid >> 5, bc = (tid & 31) * 4;

  float acc[8][8];
#pragma unroll
  for (int i = 0; i < 8; i++)
#pragma unroll
    for (int j = 0; j < 8; j++) acc[i][j] = 0.f;

  for (int k0 = 0; k0 < K; k0 += GBK) {
#pragma unroll
    for (int i = 0; i < 2; i++) {
      const int m = ar + i * 64;
      const float4 va = *(const float4*)&A[(size_t)(bm + m) * K + k0 + ac];
      As[ac + 0][m] = va.x; As[ac + 1][m] = va.y;
      As[ac + 2][m] = va.z; As[ac + 3][m] = va.w;
    }
#pragma unroll
    for (int i = 0; i < 2; i++) {
      const int kk = br + i * 8;
      *(float4*)&Bs[kk][bc] = *(const float4*)&W[(size_t)(k0 + kk) * N + bn + bc];
    }
    __syncthreads();
#pragma unroll
    for (int kk = 0; kk < GBK; kk++) {
      float a[8], b[8];
      *(float4*)&a[0] = *(const float4*)&As[kk][tr * 8];
      *(float4*)&a[4] = *(const float4*)&As[kk][tr * 8 + 4];
      *(float4*)&b[0] = *(const float4*)&Bs[kk][tc * 8];
      *(float4*)&b[4] = *(const float4*)&Bs[kk][tc * 8 + 4];
#pragma unroll
      for (int i = 0; i < 8; i++)
#pragma unroll
        for (int j = 0; j < 8; j++) acc[i][j] = fmaf(a[i], b[j], acc[i][j]);
    }
    __syncthreads();
  }
#pragma unroll
  for (int i = 0; i < 8; i++) {
    const int m = bm + tr * 8 + i;
#pragma unroll
    for (int j = 0; j < 8; j += 4) {
      const int n = bn + tc * 8 + j;
      float4 o;
      o.x = acc[i][j + 0] + bias[n + 0];
      o.y = acc[i][j + 1] + bias[n + 1];
      o.z = acc[i][j + 2] + bias[n + 2];
      o.w = acc[i][j + 3] + bias[n + 3];
      *(float4*)&C[(size_t)m * N + n] = o;
    }
  }
}

// ---------------------------------------------------------------------------
// fp32 GEMM + bias, epilogue splits result to bf16 hi + lo (x ~= hi + lo)
// ---------------------------------------------------------------------------
__global__ __launch_bounds__(256) void gemm_bias_split_kernel(
    const float* __restrict__ A, const float* __restrict__ W,
    const float* __restrict__ bias, unsigned short* __restrict__ Chi,
    unsigned short* __restrict__ Clo, int M, int N, int K) {
  __shared__ float As[GBK][GBM + 4];
  __shared__ float Bs[GBK][GBN + 4];
  const int tid = threadIdx.x;
  const int bm = blockIdx.y * GBM, bn = blockIdx.x * GBN;
  const int tr = tid >> 4, tc = tid & 15;
  const int ar = tid >> 2, ac = (tid & 3) * 4;
  const int br = tid >> 5, bc = (tid & 31) * 4;

  float acc[8][8];
#pragma unroll
  for (int i = 0; i < 8; i++)
#pragma unroll
    for (int j = 0; j < 8; j++) acc[i][j] = 0.f;

  for (int k0 = 0; k0 < K; k0 += GBK) {
#pragma unroll
    for (int i = 0; i < 2; i++) {
      const int m = ar + i * 64;
      const float4 va = *(const float4*)&A[(size_t)(bm + m) * K + k0 + ac];
      As[ac + 0][m] = va.x; As[ac + 1][m] = va.y;
      As[ac + 2][m] = va.z; As[ac + 3][m] = va.w;
    }
#pragma unroll
    for (int i = 0; i < 2; i++) {
      const int kk = br + i * 8;
      *(float4*)&Bs[kk][bc] = *(const float4*)&W[(size_t)(k0 + kk) * N + bn + bc];
    }
    __syncthreads();
#pragma unroll
    for (int kk = 0; kk < GBK; kk++) {
      float a[8], b[8];
      *(float4*)&a[0] = *(const float4*)&As[kk][tr * 8];
      *(float4*)&a[4] = *(const float4*)&As[kk][tr * 8 + 4];
      *(float4*)&b[0] = *(const float4*)&Bs[kk][tc * 8];
      *(float4*)&b[4] = *(const float4*)&Bs[kk][tc * 8 + 4];
#pragma unroll
      for (int i = 0; i < 8; i++)
#pragma unroll
        for (int j = 0; j < 8; j++) acc[i][j] = fmaf(a[i], b[j], acc[i][j]);
    }
    __syncthreads();
  }
#pragma unroll
  for (int i = 0; i < 8; i++) {
    const int m = bm + tr * 8 + i;
    const size_t base = (size_t)m * N + bn + tc * 8;
    u16x8 hv, lv;
#pragma unroll
    for (int j = 0; j < 8; j++) {
      const float o = acc[i][j] + bias[bn + tc * 8 + j];
      const unsigned short hh = f2bf(o);
      hv[j] = hh;
      lv[j] = f2bf(o - bf2f(hh));
    }
    *(u16x8*)&Chi[base] = hv;
    *(u16x8*)&Clo[base] = lv;
  }
}

// ---------------------------------------------------------------------------
// rel_key fp32 -> bf16
// ---------------------------------------------------------------------------
__global__ void rel_convert_kernel(const float* __restrict__ rel,
                                   unsigned short* __restrict__ relh) {
  const int i = blockIdx.x * 256 + threadIdx.x;
  if (i < PP * HDIM) relh[i] = f2bf(rel[i]);
}

// ---------------------------------------------------------------------------
// MFMA flash attention, bf16x3 split precision.
// Block: 256 thr = 4 waves; wave w owns query rows [16w,16w+16) of a 64-row
// query tile. KVBLK=64. Per k-tile:
//   S2 = Qh . RelWindow^T (64x128, single MFMA)  -> wave LDS scratch
//   S1 = Q . K^T (bf16x3)                        -> regs
//   bias gather S2[r][col-row+63], softmax (online), P split hi/lo -> scratch
//   PV (bf16x3) with V^T in LDS
// LDS tiles swizzled: 16B chunk c of row r at KOFF(r,c).
// ---------------------------------------------------------------------------
__global__ __launch_bounds__(256) void attn_kernel(
    const unsigned short* __restrict__ qhi, const unsigned short* __restrict__ qlo,
    const unsigned short* __restrict__ khi, const unsigned short* __restrict__ klo,
    const unsigned short* __restrict__ vhi, const unsigned short* __restrict__ vlo,
    const unsigned short* __restrict__ relh, float* __restrict__ ab) {
  __shared__ __align__(16) unsigned short Kh[4096], Kl[4096];
  __shared__ __align__(16) unsigned short Vh[4096], Vl[4096];
  __shared__ __align__(16) unsigned short Rl[8192];     // 2-slot rel ring
  __shared__ __align__(16) unsigned short Sc[9216];     // per-wave S2/P scratch

  const int tid = threadIdx.x;
  const int w = tid >> 6;          // wave 0..3
  const int l = tid & 63;
  const int ln = l & 15;           // n/col lane group
  const int lg = l >> 4;           // k-chunk group 0..3
  const int it = 31 - (int)blockIdx.x;   // reversed: longest blocks first
  const int i0 = it * 64;
  const int h = blockIdx.y;
  const int b = blockIdx.z;

  // ---- Q fragments in registers (A-operand: row=ln, k=lg*8+i, 2 k-steps) ----
  bf16x8 Aqh[2], Aql[2];
#pragma unroll
  for (int ks = 0; ks < 2; ks++) {
    const size_t qoff = ((size_t)(b * SS + i0 + w * 16 + ln)) * EE + h * 64 + ks * 32 + lg * 8;
    Aqh[ks] = *(const bf16x8*)&qhi[qoff];
    Aql[ks] = *(const bf16x8*)&qlo[qoff];
  }

  f32x4 acc[4];
#pragma unroll
  for (int nt = 0; nt < 4; nt++) acc[nt] = (f32x4){0.f, 0.f, 0.f, 0.f};
  float mrun[4] = {-1e30f, -1e30f, -1e30f, -1e30f};
  float lrun[4] = {0.f, 0.f, 0.f, 0.f};

  // staging maps
  const int sr = tid >> 2;            // 0..63 (K/rel row)
  const int sc0 = (tid & 3) * 2;      // chunk pair base
  const int vj = (tid & 31) * 2;      // V row pair
  const int vd0 = (tid >> 5) * 8;     // V col group

  // ---- prologue: stage rel block (31-it) into its slot ----
  {
    const int m = 31 - it;
    const int slot = m & 1;
    const int g = min(m * 64 + sr, PP - 1);
    const unsigned short* src = relh + (size_t)g * HDIM + sc0 * 8;
#pragma unroll
    for (int u = 0; u < 2; u++) {
      *(int4*)&Rl[slot * 4096 + KOFF(sr, sc0 + u)] = *(const int4*)(src + u * 8);
    }
  }

  const int nkt = it + 1;
  for (int kt = 0; kt < nkt; kt++) {
    const int j0 = kt * 64;
    const int b0 = 31 - it + kt;      // window base block index

    // ---- stage K (hi/lo), rel block b0+1, V^T (hi/lo) ----
    {
      const size_t krow = ((size_t)(b * SS + j0 + sr)) * EE + h * 64;
#pragma unroll
      for (int u = 0; u < 2; u++) {
        const int cc = sc0 + u;
        *(int4*)&Kh[KOFF(sr, cc)] = *(const int4*)&khi[krow + cc * 8];
        *(int4*)&Kl[KOFF(sr, cc)] = *(const int4*)&klo[krow + cc * 8];
      }
      const int m = b0 + 1;
      const int slot = m & 1;
      const int g = min(m * 64 + sr, PP - 1);
      const unsigned short* src = relh + (size_t)g * HDIM + sc0 * 8;
#pragma unroll
      for (int u = 0; u < 2; u++) {
        *(int4*)&Rl[slot * 4096 + KOFF(sr, sc0 + u)] = *(const int4*)(src + u * 8);
      }
      // V transpose: rows vj, vj+1, cols vd0..vd0+8
      const size_t vrow = ((size_t)(b * SS + j0 + vj)) * EE + h * 64 + vd0;
      const u16x8 a0 = *(const u16x8*)&vhi[vrow];
      const u16x8 a1 = *(const u16x8*)&vhi[vrow + EE];
      const u16x8 c0 = *(const u16x8*)&vlo[vrow];
      const u16x8 c1 = *(const u16x8*)&vlo[vrow + EE];
#pragma unroll
      for (int dd = 0; dd < 8; dd++) {
        const int d = vd0 + dd;
        const int off = (d << 6) + (((vj >> 3) ^ (d & 7)) << 3) + (vj & 7);
        *(unsigned int*)&Vh[off] = (unsigned int)a0[dd] | ((unsigned int)a1[dd] << 16);
        *(unsigned int*)&Vl[off] = (unsigned int)c0[dd] | ((unsigned int)c1[dd] << 16);
      }
    }
    __syncthreads();

    // ---- S2 = Qh . RelWindow^T : 8 n-tiles of 16 window cols ----
    const int scb = w * 2304;   // wave scratch base (ushort units)
#pragma unroll
    for (int n2 = 0; n2 < 8; n2++) {
      f32x4 t = (f32x4){0.f, 0.f, 0.f, 0.f};
      const int rr = (n2 * 16 + ln) & 63;
      const int slot = (b0 + (n2 >> 2)) & 1;
#pragma unroll
      for (int ks = 0; ks < 2; ks++) {
        const bf16x8 bb = *(const bf16x8*)&Rl[slot * 4096 + KOFF(rr, ks * 4 + lg)];
        t = MFMA16(Aqh[ks], bb, t);
      }
#pragma unroll
      for (int rd = 0; rd < 4; rd++)
        Sc[scb + (lg * 4 + rd) * 136 + n2 * 16 + ln] = f2bf(t[rd]);
    }
    __builtin_amdgcn_sched_barrier(0);

    // ---- S1 = Q . K^T (bf16x3) ----
    f32x4 s1[4];
#pragma unroll
    for (int nt = 0; nt < 4; nt++) {
      f32x4 s = (f32x4){0.f, 0.f, 0.f, 0.f};
      const int j = nt * 16 + ln;
#pragma unroll
      for (int ks = 0; ks < 2; ks++) {
        const bf16x8 kh = *(const bf16x8*)&Kh[KOFF(j, ks * 4 + lg)];
        const bf16x8 kl = *(const bf16x8*)&Kl[KOFF(j, ks * 4 + lg)];
        s = MFMA16(Aqh[ks], kh, s);
        s = MFMA16(Aqh[ks], kl, s);
        s = MFMA16(Aql[ks], kh, s);
      }
      s1[nt] = s;
    }

    // ---- bias gather + mask + online softmax ----
    const bool diag = (kt == it);
#pragma unroll
    for (int nt = 0; nt < 4; nt++) {
      const int col = nt * 16 + ln;
#pragma unroll
      for (int rd = 0; rd < 4; rd++) {
        const int row = lg * 4 + rd;
        const float bias = bf2f(Sc[scb + row * 136 + (col - row + 63)]);
        float s = (s1[nt][rd] + bias) * SCALE;
        if (diag && col > w * 16 + row) s = -1e30f;
        s1[nt][rd] = s;
      }
    }
    __builtin_amdgcn_sched_barrier(0);

    float corr[4];
#pragma unroll
    for (int rd = 0; rd < 4; rd++) {
      float mx = fmaxf(fmaxf(s1[0][rd], s1[1][rd]), fmaxf(s1[2][rd], s1[3][rd]));
      mx = fmaxf(mx, __shfl_xor(mx, 1));
      mx = fmaxf(mx, __shfl_xor(mx, 2));
      mx = fmaxf(mx, __shfl_xor(mx, 4));
      mx = fmaxf(mx, __shfl_xor(mx, 8));
      const float mnew = fmaxf(mrun[rd], mx);
      corr[rd] = __expf(mrun[rd] - mnew);
      mrun[rd] = mnew;
    }
#pragma unroll
    for (int nt = 0; nt < 4; nt++)
#pragma unroll
      for (int rd = 0; rd < 4; rd++) s1[nt][rd] = __expf(s1[nt][rd] - mrun[rd]);
#pragma unroll
    for (int rd = 0; rd < 4; rd++) {
      float ls = s1[0][rd] + s1[1][rd] + s1[2][rd] + s1[3][rd];
      ls += __shfl_xor(ls, 1);
      ls += __shfl_xor(ls, 2);
      ls += __shfl_xor(ls, 4);
      ls += __shfl_xor(ls, 8);
      lrun[rd] = lrun[rd] * corr[rd] + ls;
#pragma unroll
      for (int nt = 0; nt < 4; nt++) acc[nt][rd] *= corr[rd];
    }

    // ---- P split hi/lo -> wave scratch ----
#pragma unroll
    for (int nt = 0; nt < 4; nt++) {
      const int col = nt * 16 + ln;
#pragma unroll
      for (int rd = 0; rd < 4; rd++) {
        const int row = lg * 4 + rd;
        const float p = s1[nt][rd];
        const unsigned short hh = f2bf(p);
        Sc[scb + row * 72 + col] = hh;
        Sc[scb + 1152 + row * 72 + col] = f2bf(p - bf2f(hh));
      }
    }
    __builtin_amdgcn_sched_barrier(0);

    // ---- PV (bf16x3): A = P strip, B = V^T ----
    bf16x8 Ph[2], Pl[2];
#pragma unroll
    for (int ks = 0; ks < 2; ks++) {
      const int off = scb + ln * 72 + (ks * 4 + lg) * 8;
      Ph[ks] = *(const bf16x8*)&Sc[off];
      Pl[ks] = *(const bf16x8*)&Sc[off + 1152];
    }
#pragma unroll
    for (int nt = 0; nt < 4; nt++) {
      const int d = nt * 16 + ln;
#pragma unroll
      for (int ks = 0; ks < 2; ks++) {
        const bf16x8 bh = *(const bf16x8*)&Vh[KOFF(d, ks * 4 + lg)];
        const bf16x8 bl = *(const bf16x8*)&Vl[KOFF(d, ks * 4 + lg)];
        acc[nt] = MFMA16(Ph[ks], bh, acc[nt]);
        acc[nt] = MFMA16(Ph[ks], bl, acc[nt]);
        acc[nt] = MFMA16(Pl[ks], bh, acc[nt]);
      }
    }
    __syncthreads();
  }

  // ---- epilogue ----
#pragma unroll
  for (int rd = 0; rd < 4; rd++) {
    const float inv = 1.f / lrun[rd];
    const size_t orow = ((size_t)(b * SS + i0 + w * 16 + lg * 4 + rd)) * EE + h * 64;
#pragma unroll
    for (int nt = 0; nt < 4; nt++) ab[orow + nt * 16 + ln] = acc[nt][rd] * inv;
  }
}

// ---------------------------------------------------------------------------
// Launch
// ---------------------------------------------------------------------------
extern "C" void kernel_launch(void* const* d_in, const int* in_sizes, int n_in,
                              void* d_out, int out_size, void* d_ws, size_t ws_size,
                              hipStream_t stream) {
  const float* x   = (const float*)d_in[0];
  const float* Wq  = (const float*)d_in[1];
  const float* bq  = (const float*)d_in[2];
  const float* Wk  = (const float*)d_in[3];
  const float* bk  = (const float*)d_in[4];
  const float* Wv  = (const float*)d_in[5];
  const float* bv  = (const float*)d_in[6];
  const float* Wo  = (const float*)d_in[7];
  const float* bo  = (const float*)d_in[8];
  const float* rel = (const float*)d_in[9];
  float* out = (float*)d_out;

  const int M = BB * SS, N = EE, K = EE;
  const size_t SZ = (size_t)M * EE * sizeof(unsigned short);   // 8 MB

  unsigned char* w8 = (unsigned char*)d_ws;
  unsigned short* q_hi = (unsigned short*)(w8 + 0 * SZ);
  unsigned short* q_lo = (unsigned short*)(w8 + 1 * SZ);
  unsigned short* k_hi = (unsigned short*)(w8 + 2 * SZ);
  unsigned short* k_lo = (unsigned short*)(w8 + 3 * SZ);
  unsigned short* v_hi = (unsigned short*)(w8 + 4 * SZ);
  unsigned short* v_lo = (unsigned short*)(w8 + 5 * SZ);
  float* ab            = (float*)(w8 + 6 * SZ);                 // 16 MB
  unsigned short* relh = (unsigned short*)(w8 + 6 * SZ + (size_t)M * EE * sizeof(float));

  dim3 gg(N / GBN, M / GBM), gb(256);
  hipLaunchKernelGGL(gemm_bias_split_kernel, gg, gb, 0, stream, x, Wq, bq, q_hi, q_lo, M, N, K);
  hipLaunchKernelGGL(gemm_bias_split_kernel, gg, gb, 0, stream, x, Wk, bk, k_hi, k_lo, M, N, K);
  hipLaunchKernelGGL(gemm_bias_split_kernel, gg, gb, 0, stream, x, Wv, bv, v_hi, v_lo, M, N, K);
  hipLaunchKernelGGL(rel_convert_kernel, dim3((PP * HDIM + 255) / 256), gb, 0, stream, rel, relh);

  dim3 ga(SS / 64, HH, BB);
  hipLaunchKernelGGL(attn_kernel, ga, gb, 0, stream,
                     q_hi, q_lo, k_hi, k_lo, v_hi, v_lo, relh, ab);

  hipLaunchKernelGGL(gemm_bias_kernel, gg, gb, 0, stream, ab, Wo, bo, out, M, N, K);
}

// Round 7
// 580.160 us; speedup vs baseline: 4.8062x; 1.5144x over previous
//
#include <hip/hip_runtime.h>
#include <hip/hip_bf16.h>

// Problem constants: B=2, S=2048, E=1024, H=16, P=2048, HD=64
#define BB 2
#define SS 2048
#define EE 1024
#define HH 16
#define PP 2048
#define HDIM 64
#define SCALE 0.125f

typedef short bf16x8 __attribute__((ext_vector_type(8)));
typedef float f32x4 __attribute__((ext_vector_type(4)));
typedef unsigned short u16x8 __attribute__((ext_vector_type(8)));

#define MFMA16(a, b, c) __builtin_amdgcn_mfma_f32_16x16x32_bf16(a, b, c, 0, 0, 0)

__device__ __forceinline__ unsigned short f2bf(float f) {
  unsigned int u = __float_as_uint(f);
  unsigned int r = (u + 0x7FFFu + ((u >> 16) & 1u)) >> 16;
  return (unsigned short)r;
}
__device__ __forceinline__ float bf2f(unsigned short h) {
  return __uint_as_float((unsigned int)h << 16);
}
// packed u32 = lo16<<16 | hi16 (bf16 pair, x ~= hi + lo)
__device__ __forceinline__ unsigned int packbf(float f) {
  const unsigned short hh = f2bf(f);
  const unsigned short ll = f2bf(f - bf2f(hh));
  return (unsigned int)hh | ((unsigned int)ll << 16);
}
__device__ __forceinline__ void unpack8(const unsigned int* s, u16x8& h, u16x8& l) {
  const uint4 a = *(const uint4*)s;
  const uint4 b = *(const uint4*)(s + 4);
  h[0] = (unsigned short)a.x; l[0] = (unsigned short)(a.x >> 16);
  h[1] = (unsigned short)a.y; l[1] = (unsigned short)(a.y >> 16);
  h[2] = (unsigned short)a.z; l[2] = (unsigned short)(a.z >> 16);
  h[3] = (unsigned short)a.w; l[3] = (unsigned short)(a.w >> 16);
  h[4] = (unsigned short)b.x; l[4] = (unsigned short)(b.x >> 16);
  h[5] = (unsigned short)b.y; l[5] = (unsigned short)(b.y >> 16);
  h[6] = (unsigned short)b.z; l[6] = (unsigned short)(b.z >> 16);
  h[7] = (unsigned short)b.w; l[7] = (unsigned short)(b.w >> 16);
}

// swizzled 16B-chunk offset (ushort units) within a [64 rows][64 bf16] tile
#define KOFF(row, chunk) (((row) << 6) + ((((chunk) ^ ((row) & 7))) << 3))

// ---------------------------------------------------------------------------
// x fp32 -> packed bf16-pair u32
// ---------------------------------------------------------------------------
__global__ __launch_bounds__(256) void convert_pack_kernel(
    const float* __restrict__ in, unsigned int* __restrict__ out, int n4) {
  const int i = blockIdx.x * 256 + threadIdx.x;
  if (i < n4) {
    const float4 v = *(const float4*)&in[i * 4];
    uint4 o;
    o.x = packbf(v.x); o.y = packbf(v.y); o.z = packbf(v.z); o.w = packbf(v.w);
    *(uint4*)&out[i * 4] = o;
  }
}

// ---------------------------------------------------------------------------
// W fp32 [K][N] -> transposed bf16 hi/lo [N][K]
// ---------------------------------------------------------------------------
__global__ __launch_bounds__(256) void convert_wt_kernel(
    const float* __restrict__ W, unsigned short* __restrict__ Th,
    unsigned short* __restrict__ Tl) {
  __shared__ float T[32][33];
  const int tx = threadIdx.x & 31, ty = threadIdx.x >> 5;
  const int n0 = blockIdx.x * 32, k0 = blockIdx.y * 32;
#pragma unroll
  for (int j = 0; j < 4; j++)
    T[ty + j * 8][tx] = W[(size_t)(k0 + ty + j * 8) * EE + n0 + tx];
  __syncthreads();
#pragma unroll
  for (int j = 0; j < 4; j++) {
    const int nn = ty + j * 8;
    const float v = T[tx][nn];
    const unsigned short hh = f2bf(v);
    Th[(size_t)(n0 + nn) * EE + k0 + tx] = hh;
    Tl[(size_t)(n0 + nn) * EE + k0 + tx] = f2bf(v - bf2f(hh));
  }
}

// ---------------------------------------------------------------------------
// rel_key fp32 -> bf16
// ---------------------------------------------------------------------------
__global__ void rel_convert_kernel(const float* __restrict__ rel,
                                   unsigned short* __restrict__ relh) {
  const int i = blockIdx.x * 256 + threadIdx.x;
  if (i < PP * HDIM) relh[i] = f2bf(rel[i]);
}

// ---------------------------------------------------------------------------
// bf16x3 MFMA GEMM: C = A @ Wt^T + bias.  A packed u32 [M][K]; Wt hi/lo [N][K].
// 128x128 tile, BK=32, 4 waves (2x2), per-wave 64x64 (4x4 frags).
// WRITE_PACKED: 1 -> Cp packed u32, 0 -> Cf fp32.
// ---------------------------------------------------------------------------
#define TBK 32
#define LPAD 40   // ushort row stride: 80B -> 16B aligned, ~2-way banks

template <int WRITE_PACKED>
__global__ __launch_bounds__(256) void gemm_bf16x3_kernel(
    const unsigned int* __restrict__ Ap,
    const unsigned short* __restrict__ Bth, const unsigned short* __restrict__ Btl,
    const float* __restrict__ bias,
    unsigned int* __restrict__ Cp, float* __restrict__ Cf,
    int M, int N, int K) {
  __shared__ unsigned short Ah[128][LPAD], Al[128][LPAD];
  __shared__ unsigned short Bh[128][LPAD], Bl[128][LPAD];

  const int tid = threadIdx.x;
  // XCD-aware swizzle over 256 blocks (8 XCDs x 32)
  const int flat = blockIdx.x;
  const int swz = (flat & 7) * 32 + (flat >> 3);
  const int bm = (swz >> 3) * 128;
  const int bn = (swz & 7) * 128;

  const int w = tid >> 6, l = tid & 63;
  const int ln = l & 15, lg = l >> 4;
  const int wr = w >> 1, wc = w & 1;
  const int srow = tid >> 1;            // staging row 0..127
  const int skh = (tid & 1) * 16;       // k-half 0/16

  f32x4 acc[4][4];
#pragma unroll
  for (int i = 0; i < 4; i++)
#pragma unroll
    for (int j = 0; j < 4; j++) acc[i][j] = (f32x4){0.f, 0.f, 0.f, 0.f};

  for (int k0 = 0; k0 < K; k0 += TBK) {
    // ---- stage A (unpack packed u32 -> hi/lo) and B (straight copy) ----
    {
      const unsigned int* asrc = &Ap[(size_t)(bm + srow) * K + k0 + skh];
      u16x8 h0, l0, h1, l1;
      unpack8(asrc, h0, l0);
      unpack8(asrc + 8, h1, l1);
      *(u16x8*)&Ah[srow][skh] = h0; *(u16x8*)&Ah[srow][skh + 8] = h1;
      *(u16x8*)&Al[srow][skh] = l0; *(u16x8*)&Al[srow][skh + 8] = l1;
      const unsigned short* bh = &Bth[(size_t)(bn + srow) * K + k0 + skh];
      const unsigned short* bl = &Btl[(size_t)(bn + srow) * K + k0 + skh];
      *(u16x8*)&Bh[srow][skh] = *(const u16x8*)bh;
      *(u16x8*)&Bh[srow][skh + 8] = *(const u16x8*)(bh + 8);
      *(u16x8*)&Bl[srow][skh] = *(const u16x8*)bl;
      *(u16x8*)&Bl[srow][skh + 8] = *(const u16x8*)(bl + 8);
    }
    __syncthreads();

    bf16x8 afh[4], afl[4], bfh[4], bfl[4];
#pragma unroll
    for (int mi = 0; mi < 4; mi++) {
      const int r = wr * 64 + mi * 16 + ln;
      afh[mi] = *(const bf16x8*)&Ah[r][lg * 8];
      afl[mi] = *(const bf16x8*)&Al[r][lg * 8];
    }
#pragma unroll
    for (int ni = 0; ni < 4; ni++) {
      const int c = wc * 64 + ni * 16 + ln;
      bfh[ni] = *(const bf16x8*)&Bh[c][lg * 8];
      bfl[ni] = *(const bf16x8*)&Bl[c][lg * 8];
    }
#pragma unroll
    for (int mi = 0; mi < 4; mi++)
#pragma unroll
      for (int ni = 0; ni < 4; ni++) {
        acc[mi][ni] = MFMA16(afh[mi], bfh[ni], acc[mi][ni]);
        acc[mi][ni] = MFMA16(afh[mi], bfl[ni], acc[mi][ni]);
        acc[mi][ni] = MFMA16(afl[mi], bfh[ni], acc[mi][ni]);
      }
    __syncthreads();
  }

  // ---- epilogue: C/D layout col=ln, row=lg*4+rd ----
#pragma unroll
  for (int mi = 0; mi < 4; mi++)
#pragma unroll
    for (int ni = 0; ni < 4; ni++) {
      const int n = bn + wc * 64 + ni * 16 + ln;
      const float bv = bias[n];
#pragma unroll
      for (int rd = 0; rd < 4; rd++) {
        const int m = bm + wr * 64 + mi * 16 + lg * 4 + rd;
        const float o = acc[mi][ni][rd] + bv;
        if (WRITE_PACKED)
          Cp[(size_t)m * N + n] = packbf(o);
        else
          Cf[(size_t)m * N + n] = o;
      }
    }
}

// ---------------------------------------------------------------------------
// MFMA flash attention, bf16x3 split precision (inputs packed u32).
// ---------------------------------------------------------------------------
__global__ __launch_bounds__(256) void attn_kernel(
    const unsigned int* __restrict__ qp, const unsigned int* __restrict__ kp,
    const unsigned int* __restrict__ vp, const unsigned short* __restrict__ relh,
    unsigned int* __restrict__ abp) {
  __shared__ __align__(16) unsigned short Kh[4096], Kl[4096];
  __shared__ __align__(16) unsigned short Vh[4096], Vl[4096];
  __shared__ __align__(16) unsigned short Rl[8192];     // 2-slot rel ring
  __shared__ __align__(16) unsigned short Sc[9216];     // per-wave S2/P scratch

  const int tid = threadIdx.x;
  const int w = tid >> 6;
  const int l = tid & 63;
  const int ln = l & 15;
  const int lg = l >> 4;
  const int it = 31 - (int)blockIdx.x;   // reversed: longest blocks first
  const int i0 = it * 64;
  const int h = blockIdx.y;
  const int b = blockIdx.z;

  // ---- Q fragments (unpack from packed) ----
  bf16x8 Aqh[2], Aql[2];
#pragma unroll
  for (int ks = 0; ks < 2; ks++) {
    const size_t qoff = ((size_t)(b * SS + i0 + w * 16 + ln)) * EE + h * 64 + ks * 32 + lg * 8;
    u16x8 th, tl;
    unpack8(&qp[qoff], th, tl);
    Aqh[ks] = *(bf16x8*)&th;
    Aql[ks] = *(bf16x8*)&tl;
  }

  f32x4 acc[4];
#pragma unroll
  for (int nt = 0; nt < 4; nt++) acc[nt] = (f32x4){0.f, 0.f, 0.f, 0.f};
  float mrun[4] = {-1e30f, -1e30f, -1e30f, -1e30f};
  float lrun[4] = {0.f, 0.f, 0.f, 0.f};

  const int sr = tid >> 2;            // 0..63 (K/rel row)
  const int sc0 = (tid & 3) * 2;      // chunk pair base
  const int vj = (tid & 31) * 2;      // V row pair
  const int vd0 = (tid >> 5) * 8;     // V col group

  // ---- prologue: stage rel block (31-it) ----
  {
    const int m = 31 - it;
    const int slot = m & 1;
    const int g = min(m * 64 + sr, PP - 1);
    const unsigned short* src = relh + (size_t)g * HDIM + sc0 * 8;
#pragma unroll
    for (int u = 0; u < 2; u++)
      *(int4*)&Rl[slot * 4096 + KOFF(sr, sc0 + u)] = *(const int4*)(src + u * 8);
  }

  const int nkt = it + 1;
  for (int kt = 0; kt < nkt; kt++) {
    const int j0 = kt * 64;
    const int b0 = 31 - it + kt;

    // ---- stage K (unpack), rel block b0+1, V^T (unpack+transpose) ----
    {
      const size_t krow = ((size_t)(b * SS + j0 + sr)) * EE + h * 64;
#pragma unroll
      for (int u = 0; u < 2; u++) {
        const int cc = sc0 + u;
        u16x8 kh, kl;
        unpack8(&kp[krow + cc * 8], kh, kl);
        *(u16x8*)&Kh[KOFF(sr, cc)] = kh;
        *(u16x8*)&Kl[KOFF(sr, cc)] = kl;
      }
      const int m = b0 + 1;
      const int slot = m & 1;
      const int g = min(m * 64 + sr, PP - 1);
      const unsigned short* src = relh + (size_t)g * HDIM + sc0 * 8;
#pragma unroll
      for (int u = 0; u < 2; u++)
        *(int4*)&Rl[slot * 4096 + KOFF(sr, sc0 + u)] = *(const int4*)(src + u * 8);

      const size_t vrow = ((size_t)(b * SS + j0 + vj)) * EE + h * 64 + vd0;
      const uint4 r0a = *(const uint4*)&vp[vrow];
      const uint4 r0b = *(const uint4*)&vp[vrow + 4];
      const uint4 r1a = *(const uint4*)&vp[vrow + EE];
      const uint4 r1b = *(const uint4*)&vp[vrow + EE + 4];
      const unsigned int p0[8] = {r0a.x, r0a.y, r0a.z, r0a.w, r0b.x, r0b.y, r0b.z, r0b.w};
      const unsigned int p1[8] = {r1a.x, r1a.y, r1a.z, r1a.w, r1b.x, r1b.y, r1b.z, r1b.w};
#pragma unroll
      for (int dd = 0; dd < 8; dd++) {
        const int d = vd0 + dd;
        const int off = (d << 6) + (((vj >> 3) ^ (d & 7)) << 3) + (vj & 7);
        *(unsigned int*)&Vh[off] = (p0[dd] & 0xffffu) | (p1[dd] << 16);
        *(unsigned int*)&Vl[off] = (p0[dd] >> 16) | (p1[dd] & 0xffff0000u);
      }
    }
    __syncthreads();

    // ---- S2 = Qh . RelWindow^T ----
    const int scb = w * 2304;
#pragma unroll
    for (int n2 = 0; n2 < 8; n2++) {
      f32x4 t = (f32x4){0.f, 0.f, 0.f, 0.f};
      const int rr = (n2 * 16 + ln) & 63;
      const int slot = (b0 + (n2 >> 2)) & 1;
#pragma unroll
      for (int ks = 0; ks < 2; ks++) {
        const bf16x8 bb = *(const bf16x8*)&Rl[slot * 4096 + KOFF(rr, ks * 4 + lg)];
        t = MFMA16(Aqh[ks], bb, t);
      }
#pragma unroll
      for (int rd = 0; rd < 4; rd++)
        Sc[scb + (lg * 4 + rd) * 136 + n2 * 16 + ln] = f2bf(t[rd]);
    }
    __builtin_amdgcn_sched_barrier(0);

    // ---- S1 = Q . K^T (bf16x3) ----
    f32x4 s1[4];
#pragma unroll
    for (int nt = 0; nt < 4; nt++) {
      f32x4 s = (f32x4){0.f, 0.f, 0.f, 0.f};
      const int j = nt * 16 + ln;
#pragma unroll
      for (int ks = 0; ks < 2; ks++) {
        const bf16x8 kh = *(const bf16x8*)&Kh[KOFF(j, ks * 4 + lg)];
        const bf16x8 kl = *(const bf16x8*)&Kl[KOFF(j, ks * 4 + lg)];
        s = MFMA16(Aqh[ks], kh, s);
        s = MFMA16(Aqh[ks], kl, s);
        s = MFMA16(Aql[ks], kh, s);
      }
      s1[nt] = s;
    }

    // ---- bias gather + mask + online softmax ----
    const bool diag = (kt == it);
#pragma unroll
    for (int nt = 0; nt < 4; nt++) {
      const int col = nt * 16 + ln;
#pragma unroll
      for (int rd = 0; rd < 4; rd++) {
        const int row = lg * 4 + rd;
        const float bias = bf2f(Sc[scb + row * 136 + (col - row + 63)]);
        float s = (s1[nt][rd] + bias) * SCALE;
        if (diag && col > w * 16 + row) s = -1e30f;
        s1[nt][rd] = s;
      }
    }
    __builtin_amdgcn_sched_barrier(0);

    float corr[4];
#pragma unroll
    for (int rd = 0; rd < 4; rd++) {
      float mx = fmaxf(fmaxf(s1[0][rd], s1[1][rd]), fmaxf(s1[2][rd], s1[3][rd]));
      mx = fmaxf(mx, __shfl_xor(mx, 1));
      mx = fmaxf(mx, __shfl_xor(mx, 2));
      mx = fmaxf(mx, __shfl_xor(mx, 4));
      mx = fmaxf(mx, __shfl_xor(mx, 8));
      const float mnew = fmaxf(mrun[rd], mx);
      corr[rd] = __expf(mrun[rd] - mnew);
      mrun[rd] = mnew;
    }
#pragma unroll
    for (int nt = 0; nt < 4; nt++)
#pragma unroll
      for (int rd = 0; rd < 4; rd++) s1[nt][rd] = __expf(s1[nt][rd] - mrun[rd]);
#pragma unroll
    for (int rd = 0; rd < 4; rd++) {
      float ls = s1[0][rd] + s1[1][rd] + s1[2][rd] + s1[3][rd];
      ls += __shfl_xor(ls, 1);
      ls += __shfl_xor(ls, 2);
      ls += __shfl_xor(ls, 4);
      ls += __shfl_xor(ls, 8);
      lrun[rd] = lrun[rd] * corr[rd] + ls;
#pragma unroll
      for (int nt = 0; nt < 4; nt++) acc[nt][rd] *= corr[rd];
    }

    // ---- P split hi/lo -> wave scratch ----
#pragma unroll
    for (int nt = 0; nt < 4; nt++) {
      const int col = nt * 16 + ln;
#pragma unroll
      for (int rd = 0; rd < 4; rd++) {
        const int row = lg * 4 + rd;
        const float p = s1[nt][rd];
        const unsigned short hh = f2bf(p);
        Sc[scb + row * 72 + col] = hh;
        Sc[scb + 1152 + row * 72 + col] = f2bf(p - bf2f(hh));
      }
    }
    __builtin_amdgcn_sched_barrier(0);

    // ---- PV (bf16x3) ----
    bf16x8 Ph[2], Pl[2];
#pragma unroll
    for (int ks = 0; ks < 2; ks++) {
      const int off = scb + ln * 72 + (ks * 4 + lg) * 8;
      Ph[ks] = *(const bf16x8*)&Sc[off];
      Pl[ks] = *(const bf16x8*)&Sc[off + 1152];
    }
#pragma unroll
    for (int nt = 0; nt < 4; nt++) {
      const int d = nt * 16 + ln;
#pragma unroll
      for (int ks = 0; ks < 2; ks++) {
        const bf16x8 bh = *(const bf16x8*)&Vh[KOFF(d, ks * 4 + lg)];
        const bf16x8 bl = *(const bf16x8*)&Vl[KOFF(d, ks * 4 + lg)];
        acc[nt] = MFMA16(Ph[ks], bh, acc[nt]);
        acc[nt] = MFMA16(Ph[ks], bl, acc[nt]);
        acc[nt] = MFMA16(Pl[ks], bh, acc[nt]);
      }
    }
    __syncthreads();
  }

  // ---- epilogue: packed u32 out ----
#pragma unroll
  for (int rd = 0; rd < 4; rd++) {
    const float inv = 1.f / lrun[rd];
    const size_t orow = ((size_t)(b * SS + i0 + w * 16 + lg * 4 + rd)) * EE + h * 64;
#pragma unroll
    for (int nt = 0; nt < 4; nt++)
      abp[orow + nt * 16 + ln] = packbf(acc[nt][rd] * inv);
  }
}

// ---------------------------------------------------------------------------
// Launch
// ---------------------------------------------------------------------------
extern "C" void kernel_launch(void* const* d_in, const int* in_sizes, int n_in,
                              void* d_out, int out_size, void* d_ws, size_t ws_size,
                              hipStream_t stream) {
  const float* x   = (const float*)d_in[0];
  const float* Wq  = (const float*)d_in[1];
  const float* bq  = (const float*)d_in[2];
  const float* Wk  = (const float*)d_in[3];
  const float* bk  = (const float*)d_in[4];
  const float* Wv  = (const float*)d_in[5];
  const float* bv  = (const float*)d_in[6];
  const float* Wo  = (const float*)d_in[7];
  const float* bo  = (const float*)d_in[8];
  const float* rel = (const float*)d_in[9];
  float* out = (float*)d_out;

  const int M = BB * SS, N = EE, K = EE;
  const size_t PSZ = (size_t)M * EE * sizeof(unsigned int);    // 16 MB
  const size_t WSZ = (size_t)EE * EE * sizeof(unsigned short); // 2 MB

  unsigned char* w8 = (unsigned char*)d_ws;
  unsigned int* xp   = (unsigned int*)(w8);                    // also abp
  unsigned int* qpb  = (unsigned int*)(w8 + 1 * PSZ);
  unsigned int* kpb  = (unsigned int*)(w8 + 2 * PSZ);
  unsigned int* vpb  = (unsigned int*)(w8 + 3 * PSZ);
  unsigned short* wth[4], *wtl[4];
  for (int i = 0; i < 4; i++) {
    wth[i] = (unsigned short*)(w8 + 4 * PSZ + (2 * i) * WSZ);
    wtl[i] = (unsigned short*)(w8 + 4 * PSZ + (2 * i + 1) * WSZ);
  }
  unsigned short* relh = (unsigned short*)(w8 + 4 * PSZ + 8 * WSZ);
  unsigned int* abp = xp;   // x dead after QKV gemms

  // conversions
  convert_pack_kernel<<<dim3(M * K / 4 / 256), dim3(256), 0, stream>>>(x, xp, M * K / 4);
  convert_wt_kernel<<<dim3(32, 32), dim3(256), 0, stream>>>(Wq, wth[0], wtl[0]);
  convert_wt_kernel<<<dim3(32, 32), dim3(256), 0, stream>>>(Wk, wth[1], wtl[1]);
  convert_wt_kernel<<<dim3(32, 32), dim3(256), 0, stream>>>(Wv, wth[2], wtl[2]);
  convert_wt_kernel<<<dim3(32, 32), dim3(256), 0, stream>>>(Wo, wth[3], wtl[3]);
  rel_convert_kernel<<<dim3(PP * HDIM / 256), dim3(256), 0, stream>>>(rel, relh);

  // projections (bf16x3 MFMA)
  gemm_bf16x3_kernel<1><<<dim3(256), dim3(256), 0, stream>>>(
      xp, wth[0], wtl[0], bq, qpb, nullptr, M, N, K);
  gemm_bf16x3_kernel<1><<<dim3(256), dim3(256), 0, stream>>>(
      xp, wth[1], wtl[1], bk, kpb, nullptr, M, N, K);
  gemm_bf16x3_kernel<1><<<dim3(256), dim3(256), 0, stream>>>(
      xp, wth[2], wtl[2], bv, vpb, nullptr, M, N, K);

  // attention
  attn_kernel<<<dim3(SS / 64, HH, BB), dim3(256), 0, stream>>>(
      qpb, kpb, vpb, relh, abp);

  // output projection
  gemm_bf16x3_kernel<0><<<dim3(256), dim3(256), 0, stream>>>(
      abp, wth[3], wtl[3], bo, nullptr, out, M, N, K);
}

// Round 8
// 496.593 us; speedup vs baseline: 5.6150x; 1.1683x over previous
//
#include <hip/hip_runtime.h>
#include <hip/hip_bf16.h>

// Problem constants: B=2, S=2048, E=1024, H=16, P=2048, HD=64
#define BB 2
#define SS 2048
#define EE 1024
#define HH 16
#define PP 2048
#define HDIM 64
#define SCALE 0.125f

typedef short bf16x8 __attribute__((ext_vector_type(8)));
typedef float f32x4 __attribute__((ext_vector_type(4)));
typedef unsigned short u16x8 __attribute__((ext_vector_type(8)));

#define MFMA16(a, b, c) __builtin_amdgcn_mfma_f32_16x16x32_bf16(a, b, c, 0, 0, 0)

__device__ __forceinline__ unsigned short f2bf(float f) {
  unsigned int u = __float_as_uint(f);
  unsigned int r = (u + 0x7FFFu + ((u >> 16) & 1u)) >> 16;
  return (unsigned short)r;
}
__device__ __forceinline__ float bf2f(unsigned short h) {
  return __uint_as_float((unsigned int)h << 16);
}
// packed u32 = lo16<<16 | hi16 (bf16 pair, x ~= hi + lo)
__device__ __forceinline__ unsigned int packbf(float f) {
  const unsigned short hh = f2bf(f);
  const unsigned short ll = f2bf(f - bf2f(hh));
  return (unsigned int)hh | ((unsigned int)ll << 16);
}
__device__ __forceinline__ void unpack8(const unsigned int* s, u16x8& h, u16x8& l) {
  const uint4 a = *(const uint4*)s;
  const uint4 b = *(const uint4*)(s + 4);
  h[0] = (unsigned short)a.x; l[0] = (unsigned short)(a.x >> 16);
  h[1] = (unsigned short)a.y; l[1] = (unsigned short)(a.y >> 16);
  h[2] = (unsigned short)a.z; l[2] = (unsigned short)(a.z >> 16);
  h[3] = (unsigned short)a.w; l[3] = (unsigned short)(a.w >> 16);
  h[4] = (unsigned short)b.x; l[4] = (unsigned short)(b.x >> 16);
  h[5] = (unsigned short)b.y; l[5] = (unsigned short)(b.y >> 16);
  h[6] = (unsigned short)b.z; l[6] = (unsigned short)(b.z >> 16);
  h[7] = (unsigned short)b.w; l[7] = (unsigned short)(b.w >> 16);
}
__device__ __forceinline__ void unpack8_2(uint4 a, uint4 b, u16x8& h, u16x8& l) {
  h[0] = (unsigned short)a.x; l[0] = (unsigned short)(a.x >> 16);
  h[1] = (unsigned short)a.y; l[1] = (unsigned short)(a.y >> 16);
  h[2] = (unsigned short)a.z; l[2] = (unsigned short)(a.z >> 16);
  h[3] = (unsigned short)a.w; l[3] = (unsigned short)(a.w >> 16);
  h[4] = (unsigned short)b.x; l[4] = (unsigned short)(b.x >> 16);
  h[5] = (unsigned short)b.y; l[5] = (unsigned short)(b.y >> 16);
  h[6] = (unsigned short)b.z; l[6] = (unsigned short)(b.z >> 16);
  h[7] = (unsigned short)b.w; l[7] = (unsigned short)(b.w >> 16);
}

// swizzled 16B-chunk offset (ushort units) within a [64 rows][64 bf16] tile
#define KOFF(row, chunk) (((row) << 6) + ((((chunk) ^ ((row) & 7))) << 3))

// ---------------------------------------------------------------------------
// x fp32 -> packed bf16-pair u32
// ---------------------------------------------------------------------------
__global__ __launch_bounds__(256) void convert_pack_kernel(
    const float* __restrict__ in, unsigned int* __restrict__ out, int n4) {
  const int i = blockIdx.x * 256 + threadIdx.x;
  if (i < n4) {
    const float4 v = *(const float4*)&in[i * 4];
    uint4 o;
    o.x = packbf(v.x); o.y = packbf(v.y); o.z = packbf(v.z); o.w = packbf(v.w);
    *(uint4*)&out[i * 4] = o;
  }
}

// ---------------------------------------------------------------------------
// W fp32 [K][N] -> transposed bf16 hi/lo [N][K]
// ---------------------------------------------------------------------------
__global__ __launch_bounds__(256) void convert_wt_kernel(
    const float* __restrict__ W, unsigned short* __restrict__ Th,
    unsigned short* __restrict__ Tl) {
  __shared__ float T[32][33];
  const int tx = threadIdx.x & 31, ty = threadIdx.x >> 5;
  const int n0 = blockIdx.x * 32, k0 = blockIdx.y * 32;
#pragma unroll
  for (int j = 0; j < 4; j++)
    T[ty + j * 8][tx] = W[(size_t)(k0 + ty + j * 8) * EE + n0 + tx];
  __syncthreads();
#pragma unroll
  for (int j = 0; j < 4; j++) {
    const int nn = ty + j * 8;
    const float v = T[tx][nn];
    const unsigned short hh = f2bf(v);
    Th[(size_t)(n0 + nn) * EE + k0 + tx] = hh;
    Tl[(size_t)(n0 + nn) * EE + k0 + tx] = f2bf(v - bf2f(hh));
  }
}

// ---------------------------------------------------------------------------
// rel_key fp32 -> bf16
// ---------------------------------------------------------------------------
__global__ void rel_convert_kernel(const float* __restrict__ rel,
                                   unsigned short* __restrict__ relh) {
  const int i = blockIdx.x * 256 + threadIdx.x;
  if (i < PP * HDIM) relh[i] = f2bf(rel[i]);
}

// ---------------------------------------------------------------------------
// bf16x3 MFMA GEMM: C = A @ Wt^T + bias.  A packed u32 [M][K]; Wt hi/lo [N][K].
// ---------------------------------------------------------------------------
#define TBK 32
#define LPAD 40

template <int WRITE_PACKED>
__global__ __launch_bounds__(256) void gemm_bf16x3_kernel(
    const unsigned int* __restrict__ Ap,
    const unsigned short* __restrict__ Bth, const unsigned short* __restrict__ Btl,
    const float* __restrict__ bias,
    unsigned int* __restrict__ Cp, float* __restrict__ Cf,
    int M, int N, int K) {
  __shared__ unsigned short Ah[128][LPAD], Al[128][LPAD];
  __shared__ unsigned short Bh[128][LPAD], Bl[128][LPAD];

  const int tid = threadIdx.x;
  const int flat = blockIdx.x;
  const int swz = (flat & 7) * 32 + (flat >> 3);
  const int bm = (swz >> 3) * 128;
  const int bn = (swz & 7) * 128;

  const int w = tid >> 6, l = tid & 63;
  const int ln = l & 15, lg = l >> 4;
  const int wr = w >> 1, wc = w & 1;
  const int srow = tid >> 1;
  const int skh = (tid & 1) * 16;

  f32x4 acc[4][4];
#pragma unroll
  for (int i = 0; i < 4; i++)
#pragma unroll
    for (int j = 0; j < 4; j++) acc[i][j] = (f32x4){0.f, 0.f, 0.f, 0.f};

  for (int k0 = 0; k0 < K; k0 += TBK) {
    {
      const unsigned int* asrc = &Ap[(size_t)(bm + srow) * K + k0 + skh];
      u16x8 h0, l0, h1, l1;
      unpack8(asrc, h0, l0);
      unpack8(asrc + 8, h1, l1);
      *(u16x8*)&Ah[srow][skh] = h0; *(u16x8*)&Ah[srow][skh + 8] = h1;
      *(u16x8*)&Al[srow][skh] = l0; *(u16x8*)&Al[srow][skh + 8] = l1;
      const unsigned short* bh = &Bth[(size_t)(bn + srow) * K + k0 + skh];
      const unsigned short* bl = &Btl[(size_t)(bn + srow) * K + k0 + skh];
      *(u16x8*)&Bh[srow][skh] = *(const u16x8*)bh;
      *(u16x8*)&Bh[srow][skh + 8] = *(const u16x8*)(bh + 8);
      *(u16x8*)&Bl[srow][skh] = *(const u16x8*)bl;
      *(u16x8*)&Bl[srow][skh + 8] = *(const u16x8*)(bl + 8);
    }
    __syncthreads();

    bf16x8 afh[4], afl[4], bfh[4], bfl[4];
#pragma unroll
    for (int mi = 0; mi < 4; mi++) {
      const int r = wr * 64 + mi * 16 + ln;
      afh[mi] = *(const bf16x8*)&Ah[r][lg * 8];
      afl[mi] = *(const bf16x8*)&Al[r][lg * 8];
    }
#pragma unroll
    for (int ni = 0; ni < 4; ni++) {
      const int c = wc * 64 + ni * 16 + ln;
      bfh[ni] = *(const bf16x8*)&Bh[c][lg * 8];
      bfl[ni] = *(const bf16x8*)&Bl[c][lg * 8];
    }
#pragma unroll
    for (int mi = 0; mi < 4; mi++)
#pragma unroll
      for (int ni = 0; ni < 4; ni++) {
        acc[mi][ni] = MFMA16(afh[mi], bfh[ni], acc[mi][ni]);
        acc[mi][ni] = MFMA16(afh[mi], bfl[ni], acc[mi][ni]);
        acc[mi][ni] = MFMA16(afl[mi], bfh[ni], acc[mi][ni]);
      }
    __syncthreads();
  }

#pragma unroll
  for (int mi = 0; mi < 4; mi++)
#pragma unroll
    for (int ni = 0; ni < 4; ni++) {
      const int n = bn + wc * 64 + ni * 16 + ln;
      const float bv = bias[n];
#pragma unroll
      for (int rd = 0; rd < 4; rd++) {
        const int m = bm + wr * 64 + mi * 16 + lg * 4 + rd;
        const float o = acc[mi][ni][rd] + bv;
        if (WRITE_PACKED)
          Cp[(size_t)m * N + n] = packbf(o);
        else
          Cf[(size_t)m * N + n] = o;
      }
    }
}

// ---------------------------------------------------------------------------
// MFMA flash attention v2: 8 waves, QBLK=128, KVBLK=64, T14 async staging,
// per-wave-correct rel window (4-slot ring), LPT block pairing.
// Wave w owns query rows [i0+16w, i0+16w+16). Per tile:
//   S2 = Q . relWindow^T (per-wave window, slot = (M0 + (16(n2-w)>>6)) & 3)
//   S1 = Q . K^T (bf16x3); bias gather S2[row][col-row+63]; online softmax;
//   P hi/lo -> scratch; PV (bf16x3) with V^T in LDS.
// ---------------------------------------------------------------------------
__global__ __launch_bounds__(512) void attn_kernel(
    const unsigned int* __restrict__ qp, const unsigned int* __restrict__ kp,
    const unsigned int* __restrict__ vp, const unsigned short* __restrict__ relh,
    unsigned int* __restrict__ abp) {
  __shared__ __align__(16) unsigned short Kh[4096], Kl[4096];
  __shared__ __align__(16) unsigned short Vh[4096], Vl[4096];
  __shared__ __align__(16) unsigned short Rl[16384];   // 4-slot rel ring
  __shared__ __align__(16) unsigned short Sc[18432];   // 8 waves x 2304

  const int tid = threadIdx.x;
  const int w = tid >> 6;        // wave 0..7
  const int l = tid & 63;
  const int ln = l & 15;
  const int lg = l >> 4;

  // LPT pairing: fid and fid+256 land on the same CU; it' sums to 15.
  const int fid = blockIdx.x;
  const int half = fid >> 8;
  const int r8 = fid & 255;
  const int itp = half ? (r8 & 15) : 15 - (r8 & 15);
  const int h = r8 >> 4;
  const int b = half;
  const int i0 = itp * 128;
  const int nkt = 2 * itp + 2;
  const int M00 = 31 - 2 * itp;      // M0 at kt=0

  // ---- Q fragments ----
  bf16x8 Aqh[2], Aql[2];
#pragma unroll
  for (int ks = 0; ks < 2; ks++) {
    const size_t qoff = ((size_t)(b * SS + i0 + w * 16 + ln)) * EE + h * 64 + ks * 32 + lg * 8;
    u16x8 th, tl;
    unpack8(&qp[qoff], th, tl);
    Aqh[ks] = *(bf16x8*)&th;
    Aql[ks] = *(bf16x8*)&tl;
  }

  f32x4 acc[4];
#pragma unroll
  for (int nt = 0; nt < 4; nt++) acc[nt] = (f32x4){0.f, 0.f, 0.f, 0.f};
  float mrun[4] = {-1e30f, -1e30f, -1e30f, -1e30f};
  float lrun[4] = {0.f, 0.f, 0.f, 0.f};

  // staging maps (512 threads)
  const int ksr = tid >> 3, ksc = tid & 7;        // K: row, chunk
  const int vj = (tid & 31) * 2;                  // V: row pair
  const int vd0 = (tid >> 5) * 4;                 // V: 4 d-cols
  const int rr = tid >> 3, rc = tid & 7;          // rel: row, chunk

  // ---- prologue: 4 rel blocks + K/V tile 0 (direct) ----
#pragma unroll
  for (int mm = 0; mm < 4; mm++) {
    const int m = M00 - 2 + mm;
    const int g = min(max(m * 64 + rr, 0), PP - 1);
    const int4 t = *(const int4*)&relh[(size_t)g * HDIM + rc * 8];
    *(int4*)&Rl[(m & 3) * 4096 + KOFF(rr, rc)] = t;
  }
  {
    const size_t krow = ((size_t)(b * SS + ksr)) * EE + h * 64 + ksc * 8;
    const uint4 a0 = *(const uint4*)&kp[krow];
    const uint4 a1 = *(const uint4*)&kp[krow + 4];
    u16x8 kh, kl;
    unpack8_2(a0, a1, kh, kl);
    *(u16x8*)&Kh[KOFF(ksr, ksc)] = kh;
    *(u16x8*)&Kl[KOFF(ksr, ksc)] = kl;
    const size_t vrow = ((size_t)(b * SS + vj)) * EE + h * 64 + vd0;
    const uint4 v0 = *(const uint4*)&vp[vrow];
    const uint4 v1 = *(const uint4*)&vp[vrow + EE];
    const unsigned int* p0 = (const unsigned int*)&v0;
    const unsigned int* p1 = (const unsigned int*)&v1;
#pragma unroll
    for (int dd = 0; dd < 4; dd++) {
      const int d = vd0 + dd;
      const int off = (d << 6) + (((vj >> 3) ^ (d & 7)) << 3) + (vj & 7);
      *(unsigned int*)&Vh[off] = (p0[dd] & 0xffffu) | (p1[dd] << 16);
      *(unsigned int*)&Vl[off] = (p0[dd] >> 16) | (p1[dd] & 0xffff0000u);
    }
  }
  __syncthreads();

  // T14: staged-load registers for the next tile
  uint4 sk0, sk1, sv0, sv1;
  int4 srl;
  if (nkt > 1) {   // issue loads for tile 1
    const size_t krow = ((size_t)(b * SS + 64 + ksr)) * EE + h * 64 + ksc * 8;
    sk0 = *(const uint4*)&kp[krow];
    sk1 = *(const uint4*)&kp[krow + 4];
    const size_t vrow = ((size_t)(b * SS + 64 + vj)) * EE + h * 64 + vd0;
    sv0 = *(const uint4*)&vp[vrow];
    sv1 = *(const uint4*)&vp[vrow + EE];
    const int m = 1 + M00 + 1;
    const int g = min(max(m * 64 + rr, 0), PP - 1);
    srl = *(const int4*)&relh[(size_t)g * HDIM + rc * 8];
  }

  for (int kt = 0; kt < nkt; kt++) {
    const int j0 = kt * 64;
    const int M0 = kt + M00;
    const int dmax = i0 + w * 16 - j0;   // query base minus key base, per wave

    if (dmax > -16) {   // wave has at least one unmasked element this tile
      const int scb = w * 2304;

      // ---- S2 = Q . relWindow^T (per-wave window via d16 = 16(n2-w)) ----
#pragma unroll
      for (int n2 = 0; n2 < 8; n2++) {
        f32x4 t = (f32x4){0.f, 0.f, 0.f, 0.f};
        const int d16 = 16 * (n2 - w);
        const int slot = (M0 + (d16 >> 6)) & 3;
        const int rbase = d16 & 63;
#pragma unroll
        for (int ks = 0; ks < 2; ks++) {
          const bf16x8 bb = *(const bf16x8*)&Rl[slot * 4096 + KOFF(rbase + ln, ks * 4 + lg)];
          t = MFMA16(Aqh[ks], bb, t);
        }
#pragma unroll
        for (int rd = 0; rd < 4; rd++)
          Sc[scb + (lg * 4 + rd) * 136 + n2 * 16 + ln] = f2bf(t[rd]);
      }
      __builtin_amdgcn_sched_barrier(0);

      // ---- S1 = Q . K^T (bf16x3) ----
      f32x4 s1[4];
#pragma unroll
      for (int nt = 0; nt < 4; nt++) {
        f32x4 s = (f32x4){0.f, 0.f, 0.f, 0.f};
        const int j = nt * 16 + ln;
#pragma unroll
        for (int ks = 0; ks < 2; ks++) {
          const bf16x8 kh = *(const bf16x8*)&Kh[KOFF(j, ks * 4 + lg)];
          const bf16x8 kl = *(const bf16x8*)&Kl[KOFF(j, ks * 4 + lg)];
          s = MFMA16(Aqh[ks], kh, s);
          s = MFMA16(Aqh[ks], kl, s);
          s = MFMA16(Aql[ks], kh, s);
        }
        s1[nt] = s;
      }

      // ---- bias gather + mask + online softmax ----
      const bool needmask = (dmax < 63);
#pragma unroll
      for (int nt = 0; nt < 4; nt++) {
        const int col = nt * 16 + ln;
#pragma unroll
        for (int rd = 0; rd < 4; rd++) {
          const int row = lg * 4 + rd;
          const float bias = bf2f(Sc[scb + row * 136 + (col - row + 63)]);
          float s = (s1[nt][rd] + bias) * SCALE;
          if (needmask && col > dmax + row) s = -1e30f;
          s1[nt][rd] = s;
        }
      }
      __builtin_amdgcn_sched_barrier(0);

      float corr[4];
#pragma unroll
      for (int rd = 0; rd < 4; rd++) {
        float mx = fmaxf(fmaxf(s1[0][rd], s1[1][rd]), fmaxf(s1[2][rd], s1[3][rd]));
        mx = fmaxf(mx, __shfl_xor(mx, 1));
        mx = fmaxf(mx, __shfl_xor(mx, 2));
        mx = fmaxf(mx, __shfl_xor(mx, 4));
        mx = fmaxf(mx, __shfl_xor(mx, 8));
        const float mnew = fmaxf(mrun[rd], mx);
        corr[rd] = __expf(mrun[rd] - mnew);
        mrun[rd] = mnew;
      }
#pragma unroll
      for (int nt = 0; nt < 4; nt++)
#pragma unroll
        for (int rd = 0; rd < 4; rd++) s1[nt][rd] = __expf(s1[nt][rd] - mrun[rd]);
#pragma unroll
      for (int rd = 0; rd < 4; rd++) {
        float ls = s1[0][rd] + s1[1][rd] + s1[2][rd] + s1[3][rd];
        ls += __shfl_xor(ls, 1);
        ls += __shfl_xor(ls, 2);
        ls += __shfl_xor(ls, 4);
        ls += __shfl_xor(ls, 8);
        lrun[rd] = lrun[rd] * corr[rd] + ls;
#pragma unroll
        for (int nt = 0; nt < 4; nt++) acc[nt][rd] *= corr[rd];
      }

      // ---- P split hi/lo -> wave scratch ----
#pragma unroll
      for (int nt = 0; nt < 4; nt++) {
        const int col = nt * 16 + ln;
#pragma unroll
        for (int rd = 0; rd < 4; rd++) {
          const int row = lg * 4 + rd;
          const float p = s1[nt][rd];
          const unsigned short hh = f2bf(p);
          Sc[scb + row * 72 + col] = hh;
          Sc[scb + 1152 + row * 72 + col] = f2bf(p - bf2f(hh));
        }
      }
      __builtin_amdgcn_sched_barrier(0);

      // ---- PV (bf16x3) ----
      bf16x8 Ph[2], Pl[2];
#pragma unroll
      for (int ks = 0; ks < 2; ks++) {
        const int off = scb + ln * 72 + (ks * 4 + lg) * 8;
        Ph[ks] = *(const bf16x8*)&Sc[off];
        Pl[ks] = *(const bf16x8*)&Sc[off + 1152];
      }
#pragma unroll
      for (int nt = 0; nt < 4; nt++) {
        const int d = nt * 16 + ln;
#pragma unroll
        for (int ks = 0; ks < 2; ks++) {
          const bf16x8 bh = *(const bf16x8*)&Vh[KOFF(d, ks * 4 + lg)];
          const bf16x8 bl = *(const bf16x8*)&Vl[KOFF(d, ks * 4 + lg)];
          acc[nt] = MFMA16(Ph[ks], bh, acc[nt]);
          acc[nt] = MFMA16(Ph[ks], bl, acc[nt]);
          acc[nt] = MFMA16(Pl[ks], bh, acc[nt]);
        }
      }
    }
    __syncthreads();   // end of tile kt reads

    if (kt + 1 < nkt) {
      // ---- write staged tile kt+1 (regs -> LDS) ----
      {
        u16x8 kh, kl;
        unpack8_2(sk0, sk1, kh, kl);
        *(u16x8*)&Kh[KOFF(ksr, ksc)] = kh;
        *(u16x8*)&Kl[KOFF(ksr, ksc)] = kl;
        const unsigned int* p0 = (const unsigned int*)&sv0;
        const unsigned int* p1 = (const unsigned int*)&sv1;
#pragma unroll
        for (int dd = 0; dd < 4; dd++) {
          const int d = vd0 + dd;
          const int off = (d << 6) + (((vj >> 3) ^ (d & 7)) << 3) + (vj & 7);
          *(unsigned int*)&Vh[off] = (p0[dd] & 0xffffu) | (p1[dd] << 16);
          *(unsigned int*)&Vl[off] = (p0[dd] >> 16) | (p1[dd] & 0xffff0000u);
        }
        const int m = M0 + 2;    // rel block for tile kt+1
        *(int4*)&Rl[(m & 3) * 4096 + KOFF(rr, rc)] = srl;
      }
      __syncthreads();
      if (kt + 2 < nkt) {
        // ---- issue loads for tile kt+2 (hidden under compute of kt+1) ----
        const int jj = (kt + 2) * 64;
        const size_t krow = ((size_t)(b * SS + jj + ksr)) * EE + h * 64 + ksc * 8;
        sk0 = *(const uint4*)&kp[krow];
        sk1 = *(const uint4*)&kp[krow + 4];
        const size_t vrow = ((size_t)(b * SS + jj + vj)) * EE + h * 64 + vd0;
        sv0 = *(const uint4*)&vp[vrow];
        sv1 = *(const uint4*)&vp[vrow + EE];
        const int m = (kt + 2) + M00 + 1;
        const int g = min(max(m * 64 + rr, 0), PP - 1);
        srl = *(const int4*)&relh[(size_t)g * HDIM + rc * 8];
      }
    }
  }

  // ---- epilogue: packed u32 out ----
#pragma unroll
  for (int rd = 0; rd < 4; rd++) {
    const float inv = 1.f / lrun[rd];
    const size_t orow = ((size_t)(b * SS + i0 + w * 16 + lg * 4 + rd)) * EE + h * 64;
#pragma unroll
    for (int nt = 0; nt < 4; nt++)
      abp[orow + nt * 16 + ln] = packbf(acc[nt][rd] * inv);
  }
}

// ---------------------------------------------------------------------------
// Launch
// ---------------------------------------------------------------------------
extern "C" void kernel_launch(void* const* d_in, const int* in_sizes, int n_in,
                              void* d_out, int out_size, void* d_ws, size_t ws_size,
                              hipStream_t stream) {
  const float* x   = (const float*)d_in[0];
  const float* Wq  = (const float*)d_in[1];
  const float* bq  = (const float*)d_in[2];
  const float* Wk  = (const float*)d_in[3];
  const float* bk  = (const float*)d_in[4];
  const float* Wv  = (const float*)d_in[5];
  const float* bv  = (const float*)d_in[6];
  const float* Wo  = (const float*)d_in[7];
  const float* bo  = (const float*)d_in[8];
  const float* rel = (const float*)d_in[9];
  float* out = (float*)d_out;

  const int M = BB * SS, N = EE, K = EE;
  const size_t PSZ = (size_t)M * EE * sizeof(unsigned int);    // 16 MB
  const size_t WSZ = (size_t)EE * EE * sizeof(unsigned short); // 2 MB

  unsigned char* w8 = (unsigned char*)d_ws;
  unsigned int* xp   = (unsigned int*)(w8);                    // also abp
  unsigned int* qpb  = (unsigned int*)(w8 + 1 * PSZ);
  unsigned int* kpb  = (unsigned int*)(w8 + 2 * PSZ);
  unsigned int* vpb  = (unsigned int*)(w8 + 3 * PSZ);
  unsigned short* wth[4], *wtl[4];
  for (int i = 0; i < 4; i++) {
    wth[i] = (unsigned short*)(w8 + 4 * PSZ + (2 * i) * WSZ);
    wtl[i] = (unsigned short*)(w8 + 4 * PSZ + (2 * i + 1) * WSZ);
  }
  unsigned short* relh = (unsigned short*)(w8 + 4 * PSZ + 8 * WSZ);
  unsigned int* abp = xp;   // x dead after QKV gemms

  // conversions
  convert_pack_kernel<<<dim3(M * K / 4 / 256), dim3(256), 0, stream>>>(x, xp, M * K / 4);
  convert_wt_kernel<<<dim3(32, 32), dim3(256), 0, stream>>>(Wq, wth[0], wtl[0]);
  convert_wt_kernel<<<dim3(32, 32), dim3(256), 0, stream>>>(Wk, wth[1], wtl[1]);
  convert_wt_kernel<<<dim3(32, 32), dim3(256), 0, stream>>>(Wv, wth[2], wtl[2]);
  convert_wt_kernel<<<dim3(32, 32), dim3(256), 0, stream>>>(Wo, wth[3], wtl[3]);
  rel_convert_kernel<<<dim3(PP * HDIM / 256), dim3(256), 0, stream>>>(rel, relh);

  // projections (bf16x3 MFMA)
  gemm_bf16x3_kernel<1><<<dim3(256), dim3(256), 0, stream>>>(
      xp, wth[0], wtl[0], bq, qpb, nullptr, M, N, K);
  gemm_bf16x3_kernel<1><<<dim3(256), dim3(256), 0, stream>>>(
      xp, wth[1], wtl[1], bk, kpb, nullptr, M, N, K);
  gemm_bf16x3_kernel<1><<<dim3(256), dim3(256), 0, stream>>>(
      xp, wth[2], wtl[2], bv, vpb, nullptr, M, N, K);

  // attention (QBLK=128: 512 blocks x 512 threads)
  attn_kernel<<<dim3(512), dim3(512), 0, stream>>>(
      qpb, kpb, vpb, relh, abp);

  // output projection
  gemm_bf16x3_kernel<0><<<dim3(256), dim3(256), 0, stream>>>(
      abp, wth[3], wtl[3], bo, nullptr, out, M, N, K);
}

// Round 10
// 432.825 us; speedup vs baseline: 6.4422x; 1.1473x over previous
//
#include <hip/hip_runtime.h>
#include <hip/hip_bf16.h>

// Problem constants: B=2, S=2048, E=1024, H=16, P=2048, HD=64
#define BB 2
#define SS 2048
#define EE 1024
#define HH 16
#define PP 2048
#define HDIM 64
#define SCALE 0.125f
#define QKV3 3072

typedef short bf16x8 __attribute__((ext_vector_type(8)));
typedef float f32x4 __attribute__((ext_vector_type(4)));
typedef unsigned short u16x8 __attribute__((ext_vector_type(8)));

#define MFMA16(a, b, c) __builtin_amdgcn_mfma_f32_16x16x32_bf16(a, b, c, 0, 0, 0)

__device__ __forceinline__ unsigned short f2bf(float f) {
  unsigned int u = __float_as_uint(f);
  unsigned int r = (u + 0x7FFFu + ((u >> 16) & 1u)) >> 16;
  return (unsigned short)r;
}
__device__ __forceinline__ float bf2f(unsigned short h) {
  return __uint_as_float((unsigned int)h << 16);
}
// packed u32 = lo16<<16 | hi16 (bf16 pair, x ~= hi + lo)
__device__ __forceinline__ unsigned int packbf(float f) {
  const unsigned short hh = f2bf(f);
  const unsigned short ll = f2bf(f - bf2f(hh));
  return (unsigned int)hh | ((unsigned int)ll << 16);
}
__device__ __forceinline__ void unpack8(const unsigned int* s, u16x8& h, u16x8& l) {
  const uint4 a = *(const uint4*)s;
  const uint4 b = *(const uint4*)(s + 4);
  h[0] = (unsigned short)a.x; l[0] = (unsigned short)(a.x >> 16);
  h[1] = (unsigned short)a.y; l[1] = (unsigned short)(a.y >> 16);
  h[2] = (unsigned short)a.z; l[2] = (unsigned short)(a.z >> 16);
  h[3] = (unsigned short)a.w; l[3] = (unsigned short)(a.w >> 16);
  h[4] = (unsigned short)b.x; l[4] = (unsigned short)(b.x >> 16);
  h[5] = (unsigned short)b.y; l[5] = (unsigned short)(b.y >> 16);
  h[6] = (unsigned short)b.z; l[6] = (unsigned short)(b.z >> 16);
  h[7] = (unsigned short)b.w; l[7] = (unsigned short)(b.w >> 16);
}
__device__ __forceinline__ void unpack8_2(uint4 a, uint4 b, u16x8& h, u16x8& l) {
  h[0] = (unsigned short)a.x; l[0] = (unsigned short)(a.x >> 16);
  h[1] = (unsigned short)a.y; l[1] = (unsigned short)(a.y >> 16);
  h[2] = (unsigned short)a.z; l[2] = (unsigned short)(a.z >> 16);
  h[3] = (unsigned short)a.w; l[3] = (unsigned short)(a.w >> 16);
  h[4] = (unsigned short)b.x; l[4] = (unsigned short)(b.x >> 16);
  h[5] = (unsigned short)b.y; l[5] = (unsigned short)(b.y >> 16);
  h[6] = (unsigned short)b.z; l[6] = (unsigned short)(b.z >> 16);
  h[7] = (unsigned short)b.w; l[7] = (unsigned short)(b.w >> 16);
}

// swizzled 16B-chunk offset (ushort units) within a [64 rows][64 bf16] tile
#define KOFF(row, chunk) (((row) << 6) + ((((chunk) ^ ((row) & 7))) << 3))

// ---------------------------------------------------------------------------
// x fp32 -> packed bf16-pair u32
// ---------------------------------------------------------------------------
__global__ __launch_bounds__(256) void convert_pack_kernel(
    const float* __restrict__ in, unsigned int* __restrict__ out, int n4) {
  const int i = blockIdx.x * 256 + threadIdx.x;
  if (i < n4) {
    const float4 v = *(const float4*)&in[i * 4];
    uint4 o;
    o.x = packbf(v.x); o.y = packbf(v.y); o.z = packbf(v.z); o.w = packbf(v.w);
    *(uint4*)&out[i * 4] = o;
  }
}

// ---------------------------------------------------------------------------
// W fp32 [K][N] -> transposed bf16 hi/lo [N][K]
// ---------------------------------------------------------------------------
__global__ __launch_bounds__(256) void convert_wt_kernel(
    const float* __restrict__ W, unsigned short* __restrict__ Th,
    unsigned short* __restrict__ Tl) {
  __shared__ float T[32][33];
  const int tx = threadIdx.x & 31, ty = threadIdx.x >> 5;
  const int n0 = blockIdx.x * 32, k0 = blockIdx.y * 32;
#pragma unroll
  for (int j = 0; j < 4; j++)
    T[ty + j * 8][tx] = W[(size_t)(k0 + ty + j * 8) * EE + n0 + tx];
  __syncthreads();
#pragma unroll
  for (int j = 0; j < 4; j++) {
    const int nn = ty + j * 8;
    const float v = T[tx][nn];
    const unsigned short hh = f2bf(v);
    Th[(size_t)(n0 + nn) * EE + k0 + tx] = hh;
    Tl[(size_t)(n0 + nn) * EE + k0 + tx] = f2bf(v - bf2f(hh));
  }
}

// ---------------------------------------------------------------------------
// rel_key fp32 -> bf16 ; bias concat
// ---------------------------------------------------------------------------
__global__ void rel_convert_kernel(const float* __restrict__ rel,
                                   unsigned short* __restrict__ relh) {
  const int i = blockIdx.x * 256 + threadIdx.x;
  if (i < PP * HDIM) relh[i] = f2bf(rel[i]);
}
__global__ void bias_concat_kernel(const float* __restrict__ a,
                                   const float* __restrict__ b,
                                   const float* __restrict__ c,
                                   float* __restrict__ o) {
  const int i = blockIdx.x * 256 + threadIdx.x;
  if (i < QKV3)
    o[i] = (i < 1024) ? a[i] : (i < 2048 ? b[i - 1024] : c[i - 2048]);
}

// ---------------------------------------------------------------------------
// bf16x3 MFMA GEMM: C = A @ Wt^T + bias.  A packed u32 [M][K]; Wt hi/lo [N][K].
// BM=128, BNT templated (128 or 64), BK=32, 4 waves.
//   BNT=128: waves 2x2, per-wave 64x64 (acc[4][4])
//   BNT=64:  waves 2x2, per-wave 64x32 (acc[4][2])
// ---------------------------------------------------------------------------
#define TBK 32
#define LPAD 40

template <int WRITE_PACKED, int BNT>
__global__ __launch_bounds__(256) void gemm_bf16x3_kernel(
    const unsigned int* __restrict__ Ap,
    const unsigned short* __restrict__ Bth, const unsigned short* __restrict__ Btl,
    const float* __restrict__ bias,
    unsigned int* __restrict__ Cp, float* __restrict__ Cf,
    int M, int N, int K) {
  constexpr int NI = BNT / 32;          // B frags per wave
  __shared__ unsigned short Ah[128][LPAD], Al[128][LPAD];
  __shared__ unsigned short Bh[BNT][LPAD], Bl[BNT][LPAD];

  const int tid = threadIdx.x;
  // XCD-aware bijective swizzle (gridDim.x % 8 == 0 for all our grids)
  const int flat = blockIdx.x;
  const int cpx = gridDim.x >> 3;
  const int swz = (flat & 7) * cpx + (flat >> 3);
  const int nb = N / BNT;
  const int bm = (swz / nb) * 128;
  const int bn = (swz % nb) * BNT;

  const int w = tid >> 6, l = tid & 63;
  const int ln = l & 15, lg = l >> 4;
  const int wr = w >> 1, wc = w & 1;
  const int srow = tid >> 1;            // A staging row 0..127
  const int skh = (tid & 1) * 16;       // A k-half 0/16

  f32x4 acc[4][NI];
#pragma unroll
  for (int i = 0; i < 4; i++)
#pragma unroll
    for (int j = 0; j < NI; j++) acc[i][j] = (f32x4){0.f, 0.f, 0.f, 0.f};

  for (int k0 = 0; k0 < K; k0 += TBK) {
    // ---- stage A (unpack packed u32 -> hi/lo) ----
    {
      const unsigned int* asrc = &Ap[(size_t)(bm + srow) * K + k0 + skh];
      u16x8 h0, l0, h1, l1;
      unpack8(asrc, h0, l0);
      unpack8(asrc + 8, h1, l1);
      *(u16x8*)&Ah[srow][skh] = h0; *(u16x8*)&Ah[srow][skh + 8] = h1;
      *(u16x8*)&Al[srow][skh] = l0; *(u16x8*)&Al[srow][skh + 8] = l1;
    }
    // ---- stage B ----
    if constexpr (BNT == 128) {
      const unsigned short* bh = &Bth[(size_t)(bn + srow) * K + k0 + skh];
      const unsigned short* bl = &Btl[(size_t)(bn + srow) * K + k0 + skh];
      *(u16x8*)&Bh[srow][skh] = *(const u16x8*)bh;
      *(u16x8*)&Bh[srow][skh + 8] = *(const u16x8*)(bh + 8);
      *(u16x8*)&Bl[srow][skh] = *(const u16x8*)bl;
      *(u16x8*)&Bl[srow][skh + 8] = *(const u16x8*)(bl + 8);
    } else {
      const int brow = tid >> 2, bc8 = (tid & 3) * 8;
      *(u16x8*)&Bh[brow][bc8] = *(const u16x8*)&Bth[(size_t)(bn + brow) * K + k0 + bc8];
      *(u16x8*)&Bl[brow][bc8] = *(const u16x8*)&Btl[(size_t)(bn + brow) * K + k0 + bc8];
    }
    __syncthreads();

    bf16x8 afh[4], afl[4], bfh[NI], bfl[NI];
#pragma unroll
    for (int mi = 0; mi < 4; mi++) {
      const int r = wr * 64 + mi * 16 + ln;
      afh[mi] = *(const bf16x8*)&Ah[r][lg * 8];
      afl[mi] = *(const bf16x8*)&Al[r][lg * 8];
    }
#pragma unroll
    for (int ni = 0; ni < NI; ni++) {
      const int c = wc * (BNT / 2) + ni * 16 + ln;
      bfh[ni] = *(const bf16x8*)&Bh[c][lg * 8];
      bfl[ni] = *(const bf16x8*)&Bl[c][lg * 8];
    }
#pragma unroll
    for (int mi = 0; mi < 4; mi++)
#pragma unroll
      for (int ni = 0; ni < NI; ni++) {
        acc[mi][ni] = MFMA16(afh[mi], bfh[ni], acc[mi][ni]);
        acc[mi][ni] = MFMA16(afh[mi], bfl[ni], acc[mi][ni]);
        acc[mi][ni] = MFMA16(afl[mi], bfh[ni], acc[mi][ni]);
      }
    __syncthreads();
  }

  // ---- epilogue: C/D layout col=ln, row=lg*4+rd ----
#pragma unroll
  for (int mi = 0; mi < 4; mi++)
#pragma unroll
    for (int ni = 0; ni < NI; ni++) {
      const int n = bn + wc * (BNT / 2) + ni * 16 + ln;
      const float bv = bias[n];
#pragma unroll
      for (int rd = 0; rd < 4; rd++) {
        const int m = bm + wr * 64 + mi * 16 + lg * 4 + rd;
        const float o = acc[mi][ni][rd] + bv;
        if (WRITE_PACKED)
          Cp[(size_t)m * N + n] = packbf(o);
        else
          Cf[(size_t)m * N + n] = o;
      }
    }
}

// ---------------------------------------------------------------------------
// MFMA flash attention: 8 waves, QBLK=128, KVBLK=64, T14 async staging,
// per-wave rel window (4-slot ring), LPT block pairing.
// Q/K/V come from the fused QKV buffer [M][3072] at col offsets 0/1024/2048.
// PV uses P-hi only (P in [0,1]; bf16 rel err 2^-9 — within tolerance).
// ---------------------------------------------------------------------------
__global__ __launch_bounds__(512) void attn_kernel(
    const unsigned int* __restrict__ qkv, const unsigned short* __restrict__ relh,
    unsigned int* __restrict__ abp) {
  __shared__ __align__(16) unsigned short Kh[4096], Kl[4096];
  __shared__ __align__(16) unsigned short Vh[4096], Vl[4096];
  __shared__ __align__(16) unsigned short Rl[16384];   // 4-slot rel ring
  __shared__ __align__(16) unsigned short Sc[18432];   // 8 waves x 2304

  const int tid = threadIdx.x;
  const int w = tid >> 6;        // wave 0..7
  const int l = tid & 63;
  const int ln = l & 15;
  const int lg = l >> 4;

  // LPT pairing: fid and fid+256 land on the same CU; it' sums to 15.
  const int fid = blockIdx.x;
  const int half = fid >> 8;
  const int r8 = fid & 255;
  const int itp = half ? (r8 & 15) : 15 - (r8 & 15);
  const int h = r8 >> 4;
  const int b = half;
  const int i0 = itp * 128;
  const int nkt = 2 * itp + 2;
  const int M00 = 31 - 2 * itp;      // M0 at kt=0

  // ---- Q fragments ----
  bf16x8 Aqh[2], Aql[2];
#pragma unroll
  for (int ks = 0; ks < 2; ks++) {
    const size_t qoff = ((size_t)(b * SS + i0 + w * 16 + ln)) * QKV3 + h * 64 + ks * 32 + lg * 8;
    u16x8 th, tl;
    unpack8(&qkv[qoff], th, tl);
    Aqh[ks] = *(bf16x8*)&th;
    Aql[ks] = *(bf16x8*)&tl;
  }

  f32x4 acc[4];
#pragma unroll
  for (int nt = 0; nt < 4; nt++) acc[nt] = (f32x4){0.f, 0.f, 0.f, 0.f};
  float mrun[4] = {-1e30f, -1e30f, -1e30f, -1e30f};
  float lrun[4] = {0.f, 0.f, 0.f, 0.f};

  // staging maps (512 threads)
  const int ksr = tid >> 3, ksc = tid & 7;        // K: row, chunk
  const int vj = (tid & 31) * 2;                  // V: row pair
  const int vd0 = (tid >> 5) * 4;                 // V: 4 d-cols
  const int rr = tid >> 3, rc = tid & 7;          // rel: row, chunk

  // ---- prologue: 4 rel blocks + K/V tile 0 (direct) ----
#pragma unroll
  for (int mm = 0; mm < 4; mm++) {
    const int m = M00 - 2 + mm;
    const int g = min(max(m * 64 + rr, 0), PP - 1);
    const int4 t = *(const int4*)&relh[(size_t)g * HDIM + rc * 8];
    *(int4*)&Rl[(m & 3) * 4096 + KOFF(rr, rc)] = t;
  }
  {
    const size_t krow = ((size_t)(b * SS + ksr)) * QKV3 + 1024 + h * 64 + ksc * 8;
    const uint4 a0 = *(const uint4*)&qkv[krow];
    const uint4 a1 = *(const uint4*)&qkv[krow + 4];
    u16x8 kh, kl;
    unpack8_2(a0, a1, kh, kl);
    *(u16x8*)&Kh[KOFF(ksr, ksc)] = kh;
    *(u16x8*)&Kl[KOFF(ksr, ksc)] = kl;
    const size_t vrow = ((size_t)(b * SS + vj)) * QKV3 + 2048 + h * 64 + vd0;
    const uint4 v0 = *(const uint4*)&qkv[vrow];
    const uint4 v1 = *(const uint4*)&qkv[vrow + QKV3];
    const unsigned int* p0 = (const unsigned int*)&v0;
    const unsigned int* p1 = (const unsigned int*)&v1;
#pragma unroll
    for (int dd = 0; dd < 4; dd++) {
      const int d = vd0 + dd;
      const int off = (d << 6) + (((vj >> 3) ^ (d & 7)) << 3) + (vj & 7);
      *(unsigned int*)&Vh[off] = (p0[dd] & 0xffffu) | (p1[dd] << 16);
      *(unsigned int*)&Vl[off] = (p0[dd] >> 16) | (p1[dd] & 0xffff0000u);
    }
  }
  __syncthreads();

  // T14: staged-load registers for the next tile
  uint4 sk0, sk1, sv0, sv1;
  int4 srl;
  if (nkt > 1) {   // issue loads for tile 1
    const size_t krow = ((size_t)(b * SS + 64 + ksr)) * QKV3 + 1024 + h * 64 + ksc * 8;
    sk0 = *(const uint4*)&qkv[krow];
    sk1 = *(const uint4*)&qkv[krow + 4];
    const size_t vrow = ((size_t)(b * SS + 64 + vj)) * QKV3 + 2048 + h * 64 + vd0;
    sv0 = *(const uint4*)&qkv[vrow];
    sv1 = *(const uint4*)&qkv[vrow + QKV3];
    const int m = 1 + M00 + 1;
    const int g = min(max(m * 64 + rr, 0), PP - 1);
    srl = *(const int4*)&relh[(size_t)g * HDIM + rc * 8];
  }

  for (int kt = 0; kt < nkt; kt++) {
    const int j0 = kt * 64;
    const int M0 = kt + M00;
    const int dmax = i0 + w * 16 - j0;   // query base minus key base, per wave

    if (dmax > -16) {   // wave has at least one unmasked element this tile
      const int scb = w * 2304;

      // ---- S2 = Q . relWindow^T (per-wave window via d16 = 16(n2-w)) ----
#pragma unroll
      for (int n2 = 0; n2 < 8; n2++) {
        f32x4 t = (f32x4){0.f, 0.f, 0.f, 0.f};
        const int d16 = 16 * (n2 - w);
        const int slot = (M0 + (d16 >> 6)) & 3;
        const int rbase = d16 & 63;
#pragma unroll
        for (int ks = 0; ks < 2; ks++) {
          const bf16x8 bb = *(const bf16x8*)&Rl[slot * 4096 + KOFF(rbase + ln, ks * 4 + lg)];
          t = MFMA16(Aqh[ks], bb, t);
        }
#pragma unroll
        for (int rd = 0; rd < 4; rd++)
          Sc[scb + (lg * 4 + rd) * 136 + n2 * 16 + ln] = f2bf(t[rd]);
      }
      __builtin_amdgcn_sched_barrier(0);

      // ---- S1 = Q . K^T (bf16x3) ----
      f32x4 s1[4];
#pragma unroll
      for (int nt = 0; nt < 4; nt++) {
        f32x4 s = (f32x4){0.f, 0.f, 0.f, 0.f};
        const int j = nt * 16 + ln;
#pragma unroll
        for (int ks = 0; ks < 2; ks++) {
          const bf16x8 kh = *(const bf16x8*)&Kh[KOFF(j, ks * 4 + lg)];
          const bf16x8 kl = *(const bf16x8*)&Kl[KOFF(j, ks * 4 + lg)];
          s = MFMA16(Aqh[ks], kh, s);
          s = MFMA16(Aqh[ks], kl, s);
          s = MFMA16(Aql[ks], kh, s);
        }
        s1[nt] = s;
      }

      // ---- bias gather + mask + online softmax ----
      const bool needmask = (dmax < 63);
#pragma unroll
      for (int nt = 0; nt < 4; nt++) {
        const int col = nt * 16 + ln;
#pragma unroll
        for (int rd = 0; rd < 4; rd++) {
          const int row = lg * 4 + rd;
          const float bias = bf2f(Sc[scb + row * 136 + (col - row + 63)]);
          float s = (s1[nt][rd] + bias) * SCALE;
          if (needmask && col > dmax + row) s = -1e30f;
          s1[nt][rd] = s;
        }
      }
      __builtin_amdgcn_sched_barrier(0);

      float corr[4];
#pragma unroll
      for (int rd = 0; rd < 4; rd++) {
        float mx = fmaxf(fmaxf(s1[0][rd], s1[1][rd]), fmaxf(s1[2][rd], s1[3][rd]));
        mx = fmaxf(mx, __shfl_xor(mx, 1));
        mx = fmaxf(mx, __shfl_xor(mx, 2));
        mx = fmaxf(mx, __shfl_xor(mx, 4));
        mx = fmaxf(mx, __shfl_xor(mx, 8));
        const float mnew = fmaxf(mrun[rd], mx);
        corr[rd] = __expf(mrun[rd] - mnew);
        mrun[rd] = mnew;
      }
#pragma unroll
      for (int nt = 0; nt < 4; nt++)
#pragma unroll
        for (int rd = 0; rd < 4; rd++) s1[nt][rd] = __expf(s1[nt][rd] - mrun[rd]);
#pragma unroll
      for (int rd = 0; rd < 4; rd++) {
        float ls = s1[0][rd] + s1[1][rd] + s1[2][rd] + s1[3][rd];
        ls += __shfl_xor(ls, 1);
        ls += __shfl_xor(ls, 2);
        ls += __shfl_xor(ls, 4);
        ls += __shfl_xor(ls, 8);
        lrun[rd] = lrun[rd] * corr[rd] + ls;
#pragma unroll
        for (int nt = 0; nt < 4; nt++) acc[nt][rd] *= corr[rd];
      }

      // ---- P (hi only) -> wave scratch ----
#pragma unroll
      for (int nt = 0; nt < 4; nt++) {
        const int col = nt * 16 + ln;
#pragma unroll
        for (int rd = 0; rd < 4; rd++) {
          const int row = lg * 4 + rd;
          Sc[scb + row * 72 + col] = f2bf(s1[nt][rd]);
        }
      }
      __builtin_amdgcn_sched_barrier(0);

      // ---- PV: P-hi x (V-hi + V-lo) ----
      bf16x8 Ph[2];
#pragma unroll
      for (int ks = 0; ks < 2; ks++)
        Ph[ks] = *(const bf16x8*)&Sc[scb + ln * 72 + (ks * 4 + lg) * 8];
#pragma unroll
      for (int nt = 0; nt < 4; nt++) {
        const int d = nt * 16 + ln;
#pragma unroll
        for (int ks = 0; ks < 2; ks++) {
          const bf16x8 bh = *(const bf16x8*)&Vh[KOFF(d, ks * 4 + lg)];
          const bf16x8 bl = *(const bf16x8*)&Vl[KOFF(d, ks * 4 + lg)];
          acc[nt] = MFMA16(Ph[ks], bh, acc[nt]);
          acc[nt] = MFMA16(Ph[ks], bl, acc[nt]);
        }
      }
    }
    __syncthreads();   // end of tile kt reads

    if (kt + 1 < nkt) {
      // ---- write staged tile kt+1 (regs -> LDS) ----
      {
        u16x8 kh, kl;
        unpack8_2(sk0, sk1, kh, kl);
        *(u16x8*)&Kh[KOFF(ksr, ksc)] = kh;
        *(u16x8*)&Kl[KOFF(ksr, ksc)] = kl;
        const unsigned int* p0 = (const unsigned int*)&sv0;
        const unsigned int* p1 = (const unsigned int*)&sv1;
#pragma unroll
        for (int dd = 0; dd < 4; dd++) {
          const int d = vd0 + dd;
          const int off = (d << 6) + (((vj >> 3) ^ (d & 7)) << 3) + (vj & 7);
          *(unsigned int*)&Vh[off] = (p0[dd] & 0xffffu) | (p1[dd] << 16);
          *(unsigned int*)&Vl[off] = (p0[dd] >> 16) | (p1[dd] & 0xffff0000u);
        }
        const int m = M0 + 2;    // rel block for tile kt+1
        *(int4*)&Rl[(m & 3) * 4096 + KOFF(rr, rc)] = srl;
      }
      __syncthreads();
      if (kt + 2 < nkt) {
        // ---- issue loads for tile kt+2 (hidden under compute of kt+1) ----
        const int jj = (kt + 2) * 64;
        const size_t krow = ((size_t)(b * SS + jj + ksr)) * QKV3 + 1024 + h * 64 + ksc * 8;
        sk0 = *(const uint4*)&qkv[krow];
        sk1 = *(const uint4*)&qkv[krow + 4];
        const size_t vrow = ((size_t)(b * SS + jj + vj)) * QKV3 + 2048 + h * 64 + vd0;
        sv0 = *(const uint4*)&qkv[vrow];
        sv1 = *(const uint4*)&qkv[vrow + QKV3];
        const int m = (kt + 2) + M00 + 1;
        const int g = min(max(m * 64 + rr, 0), PP - 1);
        srl = *(const int4*)&relh[(size_t)g * HDIM + rc * 8];
      }
    }
  }

  // ---- epilogue: packed u32 out, [M][1024] ----
#pragma unroll
  for (int rd = 0; rd < 4; rd++) {
    const float inv = 1.f / lrun[rd];
    const size_t orow = ((size_t)(b * SS + i0 + w * 16 + lg * 4 + rd)) * EE + h * 64;
#pragma unroll
    for (int nt = 0; nt < 4; nt++)
      abp[orow + nt * 16 + ln] = packbf(acc[nt][rd] * inv);
  }
}

// ---------------------------------------------------------------------------
// Launch
// ---------------------------------------------------------------------------
extern "C" void kernel_launch(void* const* d_in, const int* in_sizes, int n_in,
                              void* d_out, int out_size, void* d_ws, size_t ws_size,
                              hipStream_t stream) {
  const float* x   = (const float*)d_in[0];
  const float* Wq  = (const float*)d_in[1];
  const float* bq  = (const float*)d_in[2];
  const float* Wk  = (const float*)d_in[3];
  const float* bk  = (const float*)d_in[4];
  const float* Wv  = (const float*)d_in[5];
  const float* bv  = (const float*)d_in[6];
  const float* Wo  = (const float*)d_in[7];
  const float* bo  = (const float*)d_in[8];
  const float* rel = (const float*)d_in[9];
  float* out = (float*)d_out;

  const int M = BB * SS, K = EE;
  const size_t MB = 1024 * 1024;

  unsigned char* w8 = (unsigned char*)d_ws;
  unsigned int* xp    = (unsigned int*)(w8);              // 16 MB (also abp)
  unsigned int* qkvp  = (unsigned int*)(w8 + 16 * MB);    // 48 MB
  unsigned short* wqh = (unsigned short*)(w8 + 64 * MB);  // 6 MB
  unsigned short* wql = (unsigned short*)(w8 + 70 * MB);  // 6 MB
  unsigned short* woh = (unsigned short*)(w8 + 76 * MB);  // 2 MB
  unsigned short* wol = (unsigned short*)(w8 + 78 * MB);  // 2 MB
  float* bqkv         = (float*)(w8 + 80 * MB);           // 12 KB
  unsigned short* relh = (unsigned short*)(w8 + 80 * MB + 65536);  // 256 KB
  unsigned int* abp = xp;   // x dead after QKV gemm

  // conversions
  convert_pack_kernel<<<dim3(M * K / 4 / 256), dim3(256), 0, stream>>>(x, xp, M * K / 4);
  convert_wt_kernel<<<dim3(32, 32), dim3(256), 0, stream>>>(Wq, wqh, wql);
  convert_wt_kernel<<<dim3(32, 32), dim3(256), 0, stream>>>(Wk, wqh + (size_t)1024 * EE, wql + (size_t)1024 * EE);
  convert_wt_kernel<<<dim3(32, 32), dim3(256), 0, stream>>>(Wv, wqh + (size_t)2048 * EE, wql + (size_t)2048 * EE);
  convert_wt_kernel<<<dim3(32, 32), dim3(256), 0, stream>>>(Wo, woh, wol);
  bias_concat_kernel<<<dim3(12), dim3(256), 0, stream>>>(bq, bk, bv, bqkv);
  rel_convert_kernel<<<dim3(PP * HDIM / 256), dim3(256), 0, stream>>>(rel, relh);

  // fused QKV projection: [M][3072] packed
  gemm_bf16x3_kernel<1, 128><<<dim3(768), dim3(256), 0, stream>>>(
      xp, wqh, wql, bqkv, qkvp, nullptr, M, QKV3, K);

  // attention (QBLK=128: 512 blocks x 512 threads)
  attn_kernel<<<dim3(512), dim3(512), 0, stream>>>(qkvp, relh, abp);

  // output projection (BN=64 for 512 blocks = 2/CU)
  gemm_bf16x3_kernel<0, 64><<<dim3(512), dim3(256), 0, stream>>>(
      abp, woh, wol, bo, nullptr, out, M, EE, K);
}

// Round 13
// 405.327 us; speedup vs baseline: 6.8793x; 1.0678x over previous
//
#include <hip/hip_runtime.h>
#include <hip/hip_bf16.h>

// Problem constants: B=2, S=2048, E=1024, H=16, P=2048, HD=64
#define BB 2
#define SS 2048
#define EE 1024
#define HH 16
#define PP 2048
#define HDIM 64
#define SCALE 0.125f
#define QKV3 3072

typedef short bf16x8 __attribute__((ext_vector_type(8)));
typedef float f32x4 __attribute__((ext_vector_type(4)));
typedef unsigned short u16x8 __attribute__((ext_vector_type(8)));

#define MFMA16(a, b, c) __builtin_amdgcn_mfma_f32_16x16x32_bf16(a, b, c, 0, 0, 0)

__device__ __forceinline__ unsigned short f2bf(float f) {
  unsigned int u = __float_as_uint(f);
  unsigned int r = (u + 0x7FFFu + ((u >> 16) & 1u)) >> 16;
  return (unsigned short)r;
}
__device__ __forceinline__ float bf2f(unsigned short h) {
  return __uint_as_float((unsigned int)h << 16);
}
// packed u32 = lo16<<16 | hi16 (bf16 pair, x ~= hi + lo)
__device__ __forceinline__ unsigned int packbf(float f) {
  const unsigned short hh = f2bf(f);
  const unsigned short ll = f2bf(f - bf2f(hh));
  return (unsigned int)hh | ((unsigned int)ll << 16);
}
__device__ __forceinline__ void unpack8(const unsigned int* s, u16x8& h, u16x8& l) {
  const uint4 a = *(const uint4*)s;
  const uint4 b = *(const uint4*)(s + 4);
  h[0] = (unsigned short)a.x; l[0] = (unsigned short)(a.x >> 16);
  h[1] = (unsigned short)a.y; l[1] = (unsigned short)(a.y >> 16);
  h[2] = (unsigned short)a.z; l[2] = (unsigned short)(a.z >> 16);
  h[3] = (unsigned short)a.w; l[3] = (unsigned short)(a.w >> 16);
  h[4] = (unsigned short)b.x; l[4] = (unsigned short)(b.x >> 16);
  h[5] = (unsigned short)b.y; l[5] = (unsigned short)(b.y >> 16);
  h[6] = (unsigned short)b.z; l[6] = (unsigned short)(b.z >> 16);
  h[7] = (unsigned short)b.w; l[7] = (unsigned short)(b.w >> 16);
}
// extract just the hi-bf16 lane (low 16 bits of each packed u32)
__device__ __forceinline__ u16x8 hi8(uint4 a, uint4 b) {
  u16x8 h;
  h[0] = (unsigned short)a.x; h[1] = (unsigned short)a.y;
  h[2] = (unsigned short)a.z; h[3] = (unsigned short)a.w;
  h[4] = (unsigned short)b.x; h[5] = (unsigned short)b.y;
  h[6] = (unsigned short)b.z; h[7] = (unsigned short)b.w;
  return h;
}

// swizzled 16B-chunk offset (ushort units) within a [64 rows][64 bf16] tile
#define KOFF(row, chunk) (((row) << 6) + ((((chunk) ^ ((row) & 7))) << 3))

// ---------------------------------------------------------------------------
// x fp32 -> packed bf16-pair u32
// ---------------------------------------------------------------------------
__global__ __launch_bounds__(256) void convert_pack_kernel(
    const float* __restrict__ in, unsigned int* __restrict__ out, int n4) {
  const int i = blockIdx.x * 256 + threadIdx.x;
  if (i < n4) {
    const float4 v = *(const float4*)&in[i * 4];
    uint4 o;
    o.x = packbf(v.x); o.y = packbf(v.y); o.z = packbf(v.z); o.w = packbf(v.w);
    *(uint4*)&out[i * 4] = o;
  }
}

// ---------------------------------------------------------------------------
// W fp32 [K][N] -> transposed bf16 hi/lo [N][K]
// ---------------------------------------------------------------------------
__global__ __launch_bounds__(256) void convert_wt_kernel(
    const float* __restrict__ W, unsigned short* __restrict__ Th,
    unsigned short* __restrict__ Tl) {
  __shared__ float T[32][33];
  const int tx = threadIdx.x & 31, ty = threadIdx.x >> 5;
  const int n0 = blockIdx.x * 32, k0 = blockIdx.y * 32;
#pragma unroll
  for (int j = 0; j < 4; j++)
    T[ty + j * 8][tx] = W[(size_t)(k0 + ty + j * 8) * EE + n0 + tx];
  __syncthreads();
#pragma unroll
  for (int j = 0; j < 4; j++) {
    const int nn = ty + j * 8;
    const float v = T[tx][nn];
    const unsigned short hh = f2bf(v);
    Th[(size_t)(n0 + nn) * EE + k0 + tx] = hh;
    Tl[(size_t)(n0 + nn) * EE + k0 + tx] = f2bf(v - bf2f(hh));
  }
}

// ---------------------------------------------------------------------------
// rel_key fp32 -> bf16 ; bias concat
// ---------------------------------------------------------------------------
__global__ void rel_convert_kernel(const float* __restrict__ rel,
                                   unsigned short* __restrict__ relh) {
  const int i = blockIdx.x * 256 + threadIdx.x;
  if (i < PP * HDIM) relh[i] = f2bf(rel[i]);
}
__global__ void bias_concat_kernel(const float* __restrict__ a,
                                   const float* __restrict__ b,
                                   const float* __restrict__ c,
                                   float* __restrict__ o) {
  const int i = blockIdx.x * 256 + threadIdx.x;
  if (i < QKV3)
    o[i] = (i < 1024) ? a[i] : (i < 2048 ? b[i - 1024] : c[i - 2048]);
}

// ---------------------------------------------------------------------------
// bf16x3 MFMA GEMM: C = A @ Wt^T + bias.  A packed u32 [M][K]; Wt hi/lo [N][K].
// BM=128, BNT templated (128 or 64), BK=32, 4 waves.
// ---------------------------------------------------------------------------
#define TBK 32
#define LPAD 40

template <int WRITE_PACKED, int BNT>
__global__ __launch_bounds__(256) void gemm_bf16x3_kernel(
    const unsigned int* __restrict__ Ap,
    const unsigned short* __restrict__ Bth, const unsigned short* __restrict__ Btl,
    const float* __restrict__ bias,
    unsigned int* __restrict__ Cp, float* __restrict__ Cf,
    int M, int N, int K) {
  constexpr int NI = BNT / 32;          // B frags per wave
  __shared__ unsigned short Ah[128][LPAD], Al[128][LPAD];
  __shared__ unsigned short Bh[BNT][LPAD], Bl[BNT][LPAD];

  const int tid = threadIdx.x;
  // XCD-aware bijective swizzle (gridDim.x % 8 == 0 for all our grids)
  const int flat = blockIdx.x;
  const int cpx = gridDim.x >> 3;
  const int swz = (flat & 7) * cpx + (flat >> 3);
  const int nb = N / BNT;
  const int bm = (swz / nb) * 128;
  const int bn = (swz % nb) * BNT;

  const int w = tid >> 6, l = tid & 63;
  const int ln = l & 15, lg = l >> 4;
  const int wr = w >> 1, wc = w & 1;
  const int srow = tid >> 1;            // A staging row 0..127
  const int skh = (tid & 1) * 16;       // A k-half 0/16

  f32x4 acc[4][NI];
#pragma unroll
  for (int i = 0; i < 4; i++)
#pragma unroll
    for (int j = 0; j < NI; j++) acc[i][j] = (f32x4){0.f, 0.f, 0.f, 0.f};

  for (int k0 = 0; k0 < K; k0 += TBK) {
    // ---- stage A (unpack packed u32 -> hi/lo) ----
    {
      const unsigned int* asrc = &Ap[(size_t)(bm + srow) * K + k0 + skh];
      u16x8 h0, l0, h1, l1;
      unpack8(asrc, h0, l0);
      unpack8(asrc + 8, h1, l1);
      *(u16x8*)&Ah[srow][skh] = h0; *(u16x8*)&Ah[srow][skh + 8] = h1;
      *(u16x8*)&Al[srow][skh] = l0; *(u16x8*)&Al[srow][skh + 8] = l1;
    }
    // ---- stage B ----
    if constexpr (BNT == 128) {
      const unsigned short* bh = &Bth[(size_t)(bn + srow) * K + k0 + skh];
      const unsigned short* bl = &Btl[(size_t)(bn + srow) * K + k0 + skh];
      *(u16x8*)&Bh[srow][skh] = *(const u16x8*)bh;
      *(u16x8*)&Bh[srow][skh + 8] = *(const u16x8*)(bh + 8);
      *(u16x8*)&Bl[srow][skh] = *(const u16x8*)bl;
      *(u16x8*)&Bl[srow][skh + 8] = *(const u16x8*)(bl + 8);
    } else {
      const int brow = tid >> 2, bc8 = (tid & 3) * 8;
      *(u16x8*)&Bh[brow][bc8] = *(const u16x8*)&Bth[(size_t)(bn + brow) * K + k0 + bc8];
      *(u16x8*)&Bl[brow][bc8] = *(const u16x8*)&Btl[(size_t)(bn + brow) * K + k0 + bc8];
    }
    __syncthreads();

    bf16x8 afh[4], afl[4], bfh[NI], bfl[NI];
#pragma unroll
    for (int mi = 0; mi < 4; mi++) {
      const int r = wr * 64 + mi * 16 + ln;
      afh[mi] = *(const bf16x8*)&Ah[r][lg * 8];
      afl[mi] = *(const bf16x8*)&Al[r][lg * 8];
    }
#pragma unroll
    for (int ni = 0; ni < NI; ni++) {
      const int c = wc * (BNT / 2) + ni * 16 + ln;
      bfh[ni] = *(const bf16x8*)&Bh[c][lg * 8];
      bfl[ni] = *(const bf16x8*)&Bl[c][lg * 8];
    }
#pragma unroll
    for (int mi = 0; mi < 4; mi++)
#pragma unroll
      for (int ni = 0; ni < NI; ni++) {
        acc[mi][ni] = MFMA16(afh[mi], bfh[ni], acc[mi][ni]);
        acc[mi][ni] = MFMA16(afh[mi], bfl[ni], acc[mi][ni]);
        acc[mi][ni] = MFMA16(afl[mi], bfh[ni], acc[mi][ni]);
      }
    __syncthreads();
  }

  // ---- epilogue: C/D layout col=ln, row=lg*4+rd ----
#pragma unroll
  for (int mi = 0; mi < 4; mi++)
#pragma unroll
    for (int ni = 0; ni < NI; ni++) {
      const int n = bn + wc * (BNT / 2) + ni * 16 + ln;
      const float bv = bias[n];
#pragma unroll
      for (int rd = 0; rd < 4; rd++) {
        const int m = bm + wr * 64 + mi * 16 + lg * 4 + rd;
        const float o = acc[mi][ni][rd] + bv;
        if (WRITE_PACKED)
          Cp[(size_t)m * N + n] = packbf(o);
        else
          Cf[(size_t)m * N + n] = o;
      }
    }
}

// ---------------------------------------------------------------------------
// MFMA flash attention v3: 8 waves, QBLK=128, KVBLK=64, T14 async staging,
// per-wave rel window (4-slot ring), LPT block pairing.
// Precision: Q split (hi+lo regs), K/V hi-only (round-3 pass at absmax 0.0352
// proves tolerance headroom; predicted absmax ~0.01-0.02).
// S2 computes only window cols [48,128) (gather range is [48,126]).
// LDS 70 KB -> 2 blocks/CU.
// ---------------------------------------------------------------------------
__global__ __launch_bounds__(512, 4) void attn_kernel(
    const unsigned int* __restrict__ qkv, const unsigned short* __restrict__ relh,
    unsigned int* __restrict__ abp) {
  __shared__ __align__(16) unsigned short Kh[4096];
  __shared__ __align__(16) unsigned short Vh[4096];
  __shared__ __align__(16) unsigned short Rl[16384];   // 4-slot rel ring
  __shared__ __align__(16) unsigned short Sc[11264];   // 8 waves x 1408

  const int tid = threadIdx.x;
  const int w = tid >> 6;        // wave 0..7
  const int l = tid & 63;
  const int ln = l & 15;
  const int lg = l >> 4;

  // LPT pairing: fid and fid+256 land on the same CU; it' sums to 15.
  const int fid = blockIdx.x;
  const int half = fid >> 8;
  const int r8 = fid & 255;
  const int itp = half ? (r8 & 15) : 15 - (r8 & 15);
  const int h = r8 >> 4;
  const int b = half;
  const int i0 = itp * 128;
  const int nkt = 2 * itp + 2;
  const int M00 = 31 - 2 * itp;      // M0 at kt=0

  // ---- Q fragments (split hi/lo, regs only) ----
  bf16x8 Aqh[2], Aql[2];
#pragma unroll
  for (int ks = 0; ks < 2; ks++) {
    const size_t qoff = ((size_t)(b * SS + i0 + w * 16 + ln)) * QKV3 + h * 64 + ks * 32 + lg * 8;
    u16x8 th, tl;
    unpack8(&qkv[qoff], th, tl);
    Aqh[ks] = *(bf16x8*)&th;
    Aql[ks] = *(bf16x8*)&tl;
  }

  f32x4 acc[4];
#pragma unroll
  for (int nt = 0; nt < 4; nt++) acc[nt] = (f32x4){0.f, 0.f, 0.f, 0.f};
  float mrun[4] = {-1e30f, -1e30f, -1e30f, -1e30f};
  float lrun[4] = {0.f, 0.f, 0.f, 0.f};

  // staging maps (512 threads)
  const int ksr = tid >> 3, ksc = tid & 7;        // K: row, chunk
  const int vj = (tid & 31) * 2;                  // V: row pair
  const int vd0 = (tid >> 5) * 4;                 // V: 4 d-cols
  const int rr = tid >> 3, rc = tid & 7;          // rel: row, chunk

  // ---- prologue: 4 rel blocks + K/V tile 0 (direct) ----
#pragma unroll
  for (int mm = 0; mm < 4; mm++) {
    const int m = M00 - 2 + mm;
    const int g = min(max(m * 64 + rr, 0), PP - 1);
    const int4 t = *(const int4*)&relh[(size_t)g * HDIM + rc * 8];
    *(int4*)&Rl[(m & 3) * 4096 + KOFF(rr, rc)] = t;
  }
  {
    const size_t krow = ((size_t)(b * SS + ksr)) * QKV3 + 1024 + h * 64 + ksc * 8;
    const uint4 a0 = *(const uint4*)&qkv[krow];
    const uint4 a1 = *(const uint4*)&qkv[krow + 4];
    *(u16x8*)&Kh[KOFF(ksr, ksc)] = hi8(a0, a1);
    const size_t vrow = ((size_t)(b * SS + vj)) * QKV3 + 2048 + h * 64 + vd0;
    const uint4 v0 = *(const uint4*)&qkv[vrow];
    const uint4 v1 = *(const uint4*)&qkv[vrow + QKV3];
    const unsigned int* p0 = (const unsigned int*)&v0;
    const unsigned int* p1 = (const unsigned int*)&v1;
#pragma unroll
    for (int dd = 0; dd < 4; dd++) {
      const int d = vd0 + dd;
      const int off = (d << 6) + (((vj >> 3) ^ (d & 7)) << 3) + (vj & 7);
      *(unsigned int*)&Vh[off] = (p0[dd] & 0xffffu) | (p1[dd] << 16);
    }
  }
  __syncthreads();

  // T14: staged-load registers for the next tile
  uint4 sk0, sk1, sv0, sv1;
  int4 srl;
  if (nkt > 1) {   // issue loads for tile 1
    const size_t krow = ((size_t)(b * SS + 64 + ksr)) * QKV3 + 1024 + h * 64 + ksc * 8;
    sk0 = *(const uint4*)&qkv[krow];
    sk1 = *(const uint4*)&qkv[krow + 4];
    const size_t vrow = ((size_t)(b * SS + 64 + vj)) * QKV3 + 2048 + h * 64 + vd0;
    sv0 = *(const uint4*)&qkv[vrow];
    sv1 = *(const uint4*)&qkv[vrow + QKV3];
    const int m = 1 + M00 + 1;
    const int g = min(max(m * 64 + rr, 0), PP - 1);
    srl = *(const int4*)&relh[(size_t)g * HDIM + rc * 8];
  }

  for (int kt = 0; kt < nkt; kt++) {
    const int j0 = kt * 64;
    const int M0 = kt + M00;
    const int dmax = i0 + w * 16 - j0;   // query base minus key base, per wave

    if (dmax > -16) {   // wave has at least one unmasked element this tile
      const int scb = w * 1408;

      // ---- S2 = Q . relWindow^T, window cols 48..127 only (n2 = 3..7) ----
#pragma unroll
      for (int n2 = 3; n2 < 8; n2++) {
        f32x4 t = (f32x4){0.f, 0.f, 0.f, 0.f};
        const int d16 = 16 * (n2 - w);
        const int slot = (M0 + (d16 >> 6)) & 3;
        const int rbase = d16 & 63;
#pragma unroll
        for (int ks = 0; ks < 2; ks++) {
          const bf16x8 bb = *(const bf16x8*)&Rl[slot * 4096 + KOFF(rbase + ln, ks * 4 + lg)];
          t = MFMA16(Aqh[ks], bb, t);
        }
#pragma unroll
        for (int rd = 0; rd < 4; rd++)
          Sc[scb + (lg * 4 + rd) * 88 + (n2 - 3) * 16 + ln] = f2bf(t[rd]);
      }
      __builtin_amdgcn_sched_barrier(0);

      // ---- S1 = Q . K^T (Q split x K hi) ----
      f32x4 s1[4];
#pragma unroll
      for (int nt = 0; nt < 4; nt++) {
        f32x4 s = (f32x4){0.f, 0.f, 0.f, 0.f};
        const int j = nt * 16 + ln;
#pragma unroll
        for (int ks = 0; ks < 2; ks++) {
          const bf16x8 kh = *(const bf16x8*)&Kh[KOFF(j, ks * 4 + lg)];
          s = MFMA16(Aqh[ks], kh, s);
          s = MFMA16(Aql[ks], kh, s);
        }
        s1[nt] = s;
      }

      // ---- bias gather (scratch col = col-row+15) + mask + online softmax ----
      const bool needmask = (dmax < 63);
#pragma unroll
      for (int nt = 0; nt < 4; nt++) {
        const int col = nt * 16 + ln;
#pragma unroll
        for (int rd = 0; rd < 4; rd++) {
          const int row = lg * 4 + rd;
          const float bias = bf2f(Sc[scb + row * 88 + (col - row + 15)]);
          float s = (s1[nt][rd] + bias) * SCALE;
          if (needmask && col > dmax + row) s = -1e30f;
          s1[nt][rd] = s;
        }
      }
      __builtin_amdgcn_sched_barrier(0);

      float corr[4];
#pragma unroll
      for (int rd = 0; rd < 4; rd++) {
        float mx = fmaxf(fmaxf(s1[0][rd], s1[1][rd]), fmaxf(s1[2][rd], s1[3][rd]));
        mx = fmaxf(mx, __shfl_xor(mx, 1));
        mx = fmaxf(mx, __shfl_xor(mx, 2));
        mx = fmaxf(mx, __shfl_xor(mx, 4));
        mx = fmaxf(mx, __shfl_xor(mx, 8));
        const float mnew = fmaxf(mrun[rd], mx);
        corr[rd] = __expf(mrun[rd] - mnew);
        mrun[rd] = mnew;
      }
#pragma unroll
      for (int nt = 0; nt < 4; nt++)
#pragma unroll
        for (int rd = 0; rd < 4; rd++) s1[nt][rd] = __expf(s1[nt][rd] - mrun[rd]);
#pragma unroll
      for (int rd = 0; rd < 4; rd++) {
        float ls = s1[0][rd] + s1[1][rd] + s1[2][rd] + s1[3][rd];
        ls += __shfl_xor(ls, 1);
        ls += __shfl_xor(ls, 2);
        ls += __shfl_xor(ls, 4);
        ls += __shfl_xor(ls, 8);
        lrun[rd] = lrun[rd] * corr[rd] + ls;
#pragma unroll
        for (int nt = 0; nt < 4; nt++) acc[nt][rd] *= corr[rd];
      }

      // ---- P (hi only) -> wave scratch (aliases S2 region; wave-local order) ----
#pragma unroll
      for (int nt = 0; nt < 4; nt++) {
        const int col = nt * 16 + ln;
#pragma unroll
        for (int rd = 0; rd < 4; rd++) {
          const int row = lg * 4 + rd;
          Sc[scb + row * 72 + col] = f2bf(s1[nt][rd]);
        }
      }
      __builtin_amdgcn_sched_barrier(0);

      // ---- PV: P-hi x V-hi ----
      bf16x8 Ph[2];
#pragma unroll
      for (int ks = 0; ks < 2; ks++)
        Ph[ks] = *(const bf16x8*)&Sc[scb + ln * 72 + (ks * 4 + lg) * 8];
#pragma unroll
      for (int nt = 0; nt < 4; nt++) {
        const int d = nt * 16 + ln;
#pragma unroll
        for (int ks = 0; ks < 2; ks++) {
          const bf16x8 bh = *(const bf16x8*)&Vh[KOFF(d, ks * 4 + lg)];
          acc[nt] = MFMA16(Ph[ks], bh, acc[nt]);
        }
      }
    }
    __syncthreads();   // end of tile kt reads

    if (kt + 1 < nkt) {
      // ---- write staged tile kt+1 (regs -> LDS) ----
      {
        *(u16x8*)&Kh[KOFF(ksr, ksc)] = hi8(sk0, sk1);
        const unsigned int* p0 = (const unsigned int*)&sv0;
        const unsigned int* p1 = (const unsigned int*)&sv1;
#pragma unroll
        for (int dd = 0; dd < 4; dd++) {
          const int d = vd0 + dd;
          const int off = (d << 6) + (((vj >> 3) ^ (d & 7)) << 3) + (vj & 7);
          *(unsigned int*)&Vh[off] = (p0[dd] & 0xffffu) | (p1[dd] << 16);
        }
        const int m = M0 + 2;    // rel block for tile kt+1
        *(int4*)&Rl[(m & 3) * 4096 + KOFF(rr, rc)] = srl;
      }
      __syncthreads();
      if (kt + 2 < nkt) {
        // ---- issue loads for tile kt+2 (hidden under compute of kt+1) ----
        const int jj = (kt + 2) * 64;
        const size_t krow = ((size_t)(b * SS + jj + ksr)) * QKV3 + 1024 + h * 64 + ksc * 8;
        sk0 = *(const uint4*)&qkv[krow];
        sk1 = *(const uint4*)&qkv[krow + 4];
        const size_t vrow = ((size_t)(b * SS + jj + vj)) * QKV3 + 2048 + h * 64 + vd0;
        sv0 = *(const uint4*)&qkv[vrow];
        sv1 = *(const uint4*)&qkv[vrow + QKV3];
        const int m = (kt + 2) + M00 + 1;
        const int g = min(max(m * 64 + rr, 0), PP - 1);
        srl = *(const int4*)&relh[(size_t)g * HDIM + rc * 8];
      }
    }
  }

  // ---- epilogue: packed u32 out, [M][1024] ----
#pragma unroll
  for (int rd = 0; rd < 4; rd++) {
    const float inv = 1.f / lrun[rd];
    const size_t orow = ((size_t)(b * SS + i0 + w * 16 + lg * 4 + rd)) * EE + h * 64;
#pragma unroll
    for (int nt = 0; nt < 4; nt++)
      abp[orow + nt * 16 + ln] = packbf(acc[nt][rd] * inv);
  }
}

// ---------------------------------------------------------------------------
// Launch
// ---------------------------------------------------------------------------
extern "C" void kernel_launch(void* const* d_in, const int* in_sizes, int n_in,
                              void* d_out, int out_size, void* d_ws, size_t ws_size,
                              hipStream_t stream) {
  const float* x   = (const float*)d_in[0];
  const float* Wq  = (const float*)d_in[1];
  const float* bq  = (const float*)d_in[2];
  const float* Wk  = (const float*)d_in[3];
  const float* bk  = (const float*)d_in[4];
  const float* Wv  = (const float*)d_in[5];
  const float* bv  = (const float*)d_in[6];
  const float* Wo  = (const float*)d_in[7];
  const float* bo  = (const float*)d_in[8];
  const float* rel = (const float*)d_in[9];
  float* out = (float*)d_out;

  const int M = BB * SS, K = EE;
  const size_t MB = 1024 * 1024;

  unsigned char* w8 = (unsigned char*)d_ws;
  unsigned int* xp    = (unsigned int*)(w8);              // 16 MB (also abp)
  unsigned int* qkvp  = (unsigned int*)(w8 + 16 * MB);    // 48 MB
  unsigned short* wqh = (unsigned short*)(w8 + 64 * MB);  // 6 MB
  unsigned short* wql = (unsigned short*)(w8 + 70 * MB);  // 6 MB
  unsigned short* woh = (unsigned short*)(w8 + 76 * MB);  // 2 MB
  unsigned short* wol = (unsigned short*)(w8 + 78 * MB);  // 2 MB
  float* bqkv         = (float*)(w8 + 80 * MB);           // 12 KB
  unsigned short* relh = (unsigned short*)(w8 + 80 * MB + 65536);  // 256 KB
  unsigned int* abp = xp;   // x dead after QKV gemm

  // conversions
  convert_pack_kernel<<<dim3(M * K / 4 / 256), dim3(256), 0, stream>>>(x, xp, M * K / 4);
  convert_wt_kernel<<<dim3(32, 32), dim3(256), 0, stream>>>(Wq, wqh, wql);
  convert_wt_kernel<<<dim3(32, 32), dim3(256), 0, stream>>>(Wk, wqh + (size_t)1024 * EE, wql + (size_t)1024 * EE);
  convert_wt_kernel<<<dim3(32, 32), dim3(256), 0, stream>>>(Wv, wqh + (size_t)2048 * EE, wql + (size_t)2048 * EE);
  convert_wt_kernel<<<dim3(32, 32), dim3(256), 0, stream>>>(Wo, woh, wol);
  bias_concat_kernel<<<dim3(12), dim3(256), 0, stream>>>(bq, bk, bv, bqkv);
  rel_convert_kernel<<<dim3(PP * HDIM / 256), dim3(256), 0, stream>>>(rel, relh);

  // fused QKV projection: [M][3072] packed
  gemm_bf16x3_kernel<1, 128><<<dim3(768), dim3(256), 0, stream>>>(
      xp, wqh, wql, bqkv, qkvp, nullptr, M, QKV3, K);

  // attention (QBLK=128: 512 blocks x 512 threads, 2 blocks/CU)
  attn_kernel<<<dim3(512), dim3(512), 0, stream>>>(qkvp, relh, abp);

  // output projection (BN=64 for 512 blocks = 2/CU)
  gemm_bf16x3_kernel<0, 64><<<dim3(512), dim3(256), 0, stream>>>(
      abp, woh, wol, bo, nullptr, out, M, EE, K);
}

// Round 14
// 363.023 us; speedup vs baseline: 7.6809x; 1.1165x over previous
//
#include <hip/hip_runtime.h>
#include <hip/hip_bf16.h>

// Problem constants: B=2, S=2048, E=1024, H=16, P=2048, HD=64
#define BB 2
#define SS 2048
#define EE 1024
#define HH 16
#define PP 2048
#define HDIM 64
#define SCALE 0.125f
#define QKV3 3072

typedef short bf16x8 __attribute__((ext_vector_type(8)));
typedef float f32x4 __attribute__((ext_vector_type(4)));
typedef unsigned short u16x8 __attribute__((ext_vector_type(8)));

#define MFMA16(a, b, c) __builtin_amdgcn_mfma_f32_16x16x32_bf16(a, b, c, 0, 0, 0)

__device__ __forceinline__ unsigned short f2bf(float f) {
  unsigned int u = __float_as_uint(f);
  unsigned int r = (u + 0x7FFFu + ((u >> 16) & 1u)) >> 16;
  return (unsigned short)r;
}
__device__ __forceinline__ float bf2f(unsigned short h) {
  return __uint_as_float((unsigned int)h << 16);
}
// async global->LDS, 16B per lane; lds base wave-uniform, +lane*16 in HW
__device__ __forceinline__ void gload16(const void* gptr, void* ldsptr) {
  __builtin_amdgcn_global_load_lds(
      (const __attribute__((address_space(1))) unsigned int*)gptr,
      (__attribute__((address_space(3))) unsigned int*)ldsptr, 16, 0, 0);
}

// swizzled 16B-chunk offset (ushort units) within a [64 rows][64 bf16] tile
#define KOFF(row, chunk) (((row) << 6) + ((((chunk) ^ ((row) & 7))) << 3))

// ---------------------------------------------------------------------------
// x fp32 -> planar bf16 hi + lo
// ---------------------------------------------------------------------------
__global__ __launch_bounds__(256) void convert_split_kernel(
    const float* __restrict__ in, unsigned short* __restrict__ oh,
    unsigned short* __restrict__ ol, int n4) {
  const int i = blockIdx.x * 256 + threadIdx.x;
  if (i < n4) {
    const float4 v = *(const float4*)&in[i * 4];
    ushort4 h, l;
    h.x = f2bf(v.x); l.x = f2bf(v.x - bf2f(h.x));
    h.y = f2bf(v.y); l.y = f2bf(v.y - bf2f(h.y));
    h.z = f2bf(v.z); l.z = f2bf(v.z - bf2f(h.z));
    h.w = f2bf(v.w); l.w = f2bf(v.w - bf2f(h.w));
    *(ushort4*)&oh[i * 4] = h;
    *(ushort4*)&ol[i * 4] = l;
  }
}

// ---------------------------------------------------------------------------
// W fp32 [K][N] -> transposed bf16 hi/lo [N][K]
// ---------------------------------------------------------------------------
__global__ __launch_bounds__(256) void convert_wt_kernel(
    const float* __restrict__ W, unsigned short* __restrict__ Th,
    unsigned short* __restrict__ Tl) {
  __shared__ float T[32][33];
  const int tx = threadIdx.x & 31, ty = threadIdx.x >> 5;
  const int n0 = blockIdx.x * 32, k0 = blockIdx.y * 32;
#pragma unroll
  for (int j = 0; j < 4; j++)
    T[ty + j * 8][tx] = W[(size_t)(k0 + ty + j * 8) * EE + n0 + tx];
  __syncthreads();
#pragma unroll
  for (int j = 0; j < 4; j++) {
    const int nn = ty + j * 8;
    const float v = T[tx][nn];
    const unsigned short hh = f2bf(v);
    Th[(size_t)(n0 + nn) * EE + k0 + tx] = hh;
    Tl[(size_t)(n0 + nn) * EE + k0 + tx] = f2bf(v - bf2f(hh));
  }
}

// ---------------------------------------------------------------------------
// rel_key fp32 -> bf16 ; bias concat
// ---------------------------------------------------------------------------
__global__ void rel_convert_kernel(const float* __restrict__ rel,
                                   unsigned short* __restrict__ relh) {
  const int i = blockIdx.x * 256 + threadIdx.x;
  if (i < PP * HDIM) relh[i] = f2bf(rel[i]);
}
__global__ void bias_concat_kernel(const float* __restrict__ a,
                                   const float* __restrict__ b,
                                   const float* __restrict__ c,
                                   float* __restrict__ o) {
  const int i = blockIdx.x * 256 + threadIdx.x;
  if (i < QKV3)
    o[i] = (i < 1024) ? a[i] : (i < 2048 ? b[i - 1024] : c[i - 2048]);
}

// ---------------------------------------------------------------------------
// bf16x3 MFMA GEMM, planar hi/lo + global_load_lds staging.
// A planes [M][K]; Wt planes [N][K]. BM=128, BNT in {128,64}, BK=32, 4 waves.
// LDS tile [rows][8 chunks x 16B]: chunks 0-3 = hi k-chunks, 4-7 = lo.
// Stored with XOR swizzle: position p of row r holds logical chunk p^(r&7);
// source address pre-swizzled so gload dest stays linear (rule #21).
// WRITE_SPLIT: 1 -> Ch/Cl planar bf16, 0 -> Cf fp32.
// ---------------------------------------------------------------------------
#define TBK 32

template <int WRITE_SPLIT, int BNT>
__global__ __launch_bounds__(256) void gemm_planar_kernel(
    const unsigned short* __restrict__ Ahg, const unsigned short* __restrict__ Alg,
    const unsigned short* __restrict__ Bhg, const unsigned short* __restrict__ Blg,
    const float* __restrict__ bias,
    unsigned short* __restrict__ Ch, unsigned short* __restrict__ Cl,
    float* __restrict__ Cf, int M, int N, int K) {
  constexpr int NI = BNT / 32;              // B frags per wave
  constexpr int BCH = BNT * 8;              // B chunks per tile
  __shared__ __align__(16) unsigned short As[128 * 64];   // 16 KB
  __shared__ __align__(16) unsigned short Bs[BNT * 64];

  const int tid = threadIdx.x;
  // XCD-aware bijective swizzle (gridDim.x % 8 == 0 for all our grids)
  const int flat = blockIdx.x;
  const int cpx = gridDim.x >> 3;
  const int swz = (flat & 7) * cpx + (flat >> 3);
  const int nb = N / BNT;
  const int bm = (swz / nb) * 128;
  const int bn = (swz % nb) * BNT;

  const int wv = tid >> 6, lane = tid & 63;
  const int ln = lane & 15, lg = lane >> 4;
  const int wr = wv >> 1, wc = wv & 1;

  f32x4 acc[4][NI];
#pragma unroll
  for (int i = 0; i < 4; i++)
#pragma unroll
    for (int j = 0; j < NI; j++) acc[i][j] = (f32x4){0.f, 0.f, 0.f, 0.f};

  for (int k0 = 0; k0 < K; k0 += TBK) {
    // ---- stage A: 1024 chunks, 4 calls/wave ----
#pragma unroll
    for (int j = 0; j < 4; j++) {
      const int t = wv * 256 + j * 64 + lane;
      const int row = t >> 3;
      const int c = (t & 7) ^ (row & 7);    // pre-swizzled source chunk
      const unsigned short* src = (c < 4)
          ? &Ahg[(size_t)(bm + row) * K + k0 + c * 8]
          : &Alg[(size_t)(bm + row) * K + k0 + (c - 4) * 8];
      gload16(src, &As[(size_t)(wv * 256 + j * 64) * 8]);
    }
    // ---- stage B: BCH chunks ----
#pragma unroll
    for (int j = 0; j < BCH / 256; j++) {
      const int t = wv * (BCH / 4) + j * 64 + lane;
      const int row = t >> 3;
      const int c = (t & 7) ^ (row & 7);
      const unsigned short* src = (c < 4)
          ? &Bhg[(size_t)(bn + row) * K + k0 + c * 8]
          : &Blg[(size_t)(bn + row) * K + k0 + (c - 4) * 8];
      gload16(src, &Bs[(size_t)(wv * (BCH / 4) + j * 64) * 8]);
    }
    __syncthreads();

    bf16x8 afh[4], afl[4], bfh[NI], bfl[NI];
#pragma unroll
    for (int mi = 0; mi < 4; mi++) {
      const int r = wr * 64 + mi * 16 + ln;
      afh[mi] = *(const bf16x8*)&As[(size_t)r * 64 + ((lg ^ (r & 7)) << 3)];
      afl[mi] = *(const bf16x8*)&As[(size_t)r * 64 + (((lg + 4) ^ (r & 7)) << 3)];
    }
#pragma unroll
    for (int ni = 0; ni < NI; ni++) {
      const int c = wc * (BNT / 2) + ni * 16 + ln;
      bfh[ni] = *(const bf16x8*)&Bs[(size_t)c * 64 + ((lg ^ (c & 7)) << 3)];
      bfl[ni] = *(const bf16x8*)&Bs[(size_t)c * 64 + (((lg + 4) ^ (c & 7)) << 3)];
    }
#pragma unroll
    for (int mi = 0; mi < 4; mi++)
#pragma unroll
      for (int ni = 0; ni < NI; ni++) {
        acc[mi][ni] = MFMA16(afh[mi], bfh[ni], acc[mi][ni]);
        acc[mi][ni] = MFMA16(afh[mi], bfl[ni], acc[mi][ni]);
        acc[mi][ni] = MFMA16(afl[mi], bfh[ni], acc[mi][ni]);
      }
    __syncthreads();
  }

  // ---- epilogue: C/D layout col=ln, row=lg*4+rd ----
#pragma unroll
  for (int mi = 0; mi < 4; mi++)
#pragma unroll
    for (int ni = 0; ni < NI; ni++) {
      const int n = bn + wc * (BNT / 2) + ni * 16 + ln;
      const float bv = bias[n];
#pragma unroll
      for (int rd = 0; rd < 4; rd++) {
        const int m = bm + wr * 64 + mi * 16 + lg * 4 + rd;
        const float o = acc[mi][ni][rd] + bv;
        if (WRITE_SPLIT) {
          const unsigned short hh = f2bf(o);
          Ch[(size_t)m * N + n] = hh;
          Cl[(size_t)m * N + n] = f2bf(o - bf2f(hh));
        } else {
          Cf[(size_t)m * N + n] = o;
        }
      }
    }
}

// ---------------------------------------------------------------------------
// MFMA flash attention v3 (planar inputs): 8 waves, QBLK=128, KVBLK=64,
// T14 async staging, per-wave rel window (4-slot ring), LPT block pairing.
// Q split (hi+lo regs), K/V hi-plane only. S2 window cols [48,128) only.
// LDS 70 KB -> 2 blocks/CU. Arithmetic identical to round-13 kernel.
// ---------------------------------------------------------------------------
__global__ __launch_bounds__(512, 4) void attn_kernel(
    const unsigned short* __restrict__ qkvh, const unsigned short* __restrict__ qkvl,
    const unsigned short* __restrict__ relh,
    unsigned short* __restrict__ abh, unsigned short* __restrict__ abl) {
  __shared__ __align__(16) unsigned short Kh[4096];
  __shared__ __align__(16) unsigned short Vh[4096];
  __shared__ __align__(16) unsigned short Rl[16384];   // 4-slot rel ring
  __shared__ __align__(16) unsigned short Sc[11264];   // 8 waves x 1408

  const int tid = threadIdx.x;
  const int w = tid >> 6;        // wave 0..7
  const int l = tid & 63;
  const int ln = l & 15;
  const int lg = l >> 4;

  // LPT pairing: fid and fid+256 land on the same CU; it' sums to 15.
  const int fid = blockIdx.x;
  const int half = fid >> 8;
  const int r8 = fid & 255;
  const int itp = half ? (r8 & 15) : 15 - (r8 & 15);
  const int h = r8 >> 4;
  const int b = half;
  const int i0 = itp * 128;
  const int nkt = 2 * itp + 2;
  const int M00 = 31 - 2 * itp;      // M0 at kt=0

  // ---- Q fragments (split hi/lo from planar) ----
  bf16x8 Aqh[2], Aql[2];
#pragma unroll
  for (int ks = 0; ks < 2; ks++) {
    const size_t qoff = ((size_t)(b * SS + i0 + w * 16 + ln)) * QKV3 + h * 64 + ks * 32 + lg * 8;
    Aqh[ks] = *(const bf16x8*)&qkvh[qoff];
    Aql[ks] = *(const bf16x8*)&qkvl[qoff];
  }

  f32x4 acc[4];
#pragma unroll
  for (int nt = 0; nt < 4; nt++) acc[nt] = (f32x4){0.f, 0.f, 0.f, 0.f};
  float mrun[4] = {-1e30f, -1e30f, -1e30f, -1e30f};
  float lrun[4] = {0.f, 0.f, 0.f, 0.f};

  // staging maps (512 threads)
  const int ksr = tid >> 3, ksc = tid & 7;        // K: row, chunk
  const int vj = (tid & 31) * 2;                  // V: row pair
  const int vd0 = (tid >> 5) * 4;                 // V: 4 d-cols
  const int rr = tid >> 3, rc = tid & 7;          // rel: row, chunk

  // ---- prologue: 4 rel blocks + K/V tile 0 (direct) ----
#pragma unroll
  for (int mm = 0; mm < 4; mm++) {
    const int m = M00 - 2 + mm;
    const int g = min(max(m * 64 + rr, 0), PP - 1);
    const int4 t = *(const int4*)&relh[(size_t)g * HDIM + rc * 8];
    *(int4*)&Rl[(m & 3) * 4096 + KOFF(rr, rc)] = t;
  }
  {
    const size_t krow = ((size_t)(b * SS + ksr)) * QKV3 + 1024 + h * 64 + ksc * 8;
    *(u16x8*)&Kh[KOFF(ksr, ksc)] = *(const u16x8*)&qkvh[krow];
    const size_t vrow = ((size_t)(b * SS + vj)) * QKV3 + 2048 + h * 64 + vd0;
    const ushort4 v0 = *(const ushort4*)&qkvh[vrow];
    const ushort4 v1 = *(const ushort4*)&qkvh[vrow + QKV3];
    const unsigned short p0[4] = {v0.x, v0.y, v0.z, v0.w};
    const unsigned short p1[4] = {v1.x, v1.y, v1.z, v1.w};
#pragma unroll
    for (int dd = 0; dd < 4; dd++) {
      const int d = vd0 + dd;
      const int off = (d << 6) + (((vj >> 3) ^ (d & 7)) << 3) + (vj & 7);
      *(unsigned int*)&Vh[off] = (unsigned int)p0[dd] | ((unsigned int)p1[dd] << 16);
    }
  }
  __syncthreads();

  // T14: staged-load registers for the next tile
  uint4 sk;
  ushort4 sv0, sv1;
  int4 srl;
  if (nkt > 1) {   // issue loads for tile 1
    const size_t krow = ((size_t)(b * SS + 64 + ksr)) * QKV3 + 1024 + h * 64 + ksc * 8;
    sk = *(const uint4*)&qkvh[krow];
    const size_t vrow = ((size_t)(b * SS + 64 + vj)) * QKV3 + 2048 + h * 64 + vd0;
    sv0 = *(const ushort4*)&qkvh[vrow];
    sv1 = *(const ushort4*)&qkvh[vrow + QKV3];
    const int m = 1 + M00 + 1;
    const int g = min(max(m * 64 + rr, 0), PP - 1);
    srl = *(const int4*)&relh[(size_t)g * HDIM + rc * 8];
  }

  for (int kt = 0; kt < nkt; kt++) {
    const int j0 = kt * 64;
    const int M0 = kt + M00;
    const int dmax = i0 + w * 16 - j0;   // query base minus key base, per wave

    if (dmax > -16) {   // wave has at least one unmasked element this tile
      const int scb = w * 1408;

      // ---- S2 = Q . relWindow^T, window cols 48..127 only (n2 = 3..7) ----
#pragma unroll
      for (int n2 = 3; n2 < 8; n2++) {
        f32x4 t = (f32x4){0.f, 0.f, 0.f, 0.f};
        const int d16 = 16 * (n2 - w);
        const int slot = (M0 + (d16 >> 6)) & 3;
        const int rbase = d16 & 63;
#pragma unroll
        for (int ks = 0; ks < 2; ks++) {
          const bf16x8 bb = *(const bf16x8*)&Rl[slot * 4096 + KOFF(rbase + ln, ks * 4 + lg)];
          t = MFMA16(Aqh[ks], bb, t);
        }
#pragma unroll
        for (int rd = 0; rd < 4; rd++)
          Sc[scb + (lg * 4 + rd) * 88 + (n2 - 3) * 16 + ln] = f2bf(t[rd]);
      }
      __builtin_amdgcn_sched_barrier(0);

      // ---- S1 = Q . K^T (Q split x K hi) ----
      f32x4 s1[4];
#pragma unroll
      for (int nt = 0; nt < 4; nt++) {
        f32x4 s = (f32x4){0.f, 0.f, 0.f, 0.f};
        const int j = nt * 16 + ln;
#pragma unroll
        for (int ks = 0; ks < 2; ks++) {
          const bf16x8 kh = *(const bf16x8*)&Kh[KOFF(j, ks * 4 + lg)];
          s = MFMA16(Aqh[ks], kh, s);
          s = MFMA16(Aql[ks], kh, s);
        }
        s1[nt] = s;
      }

      // ---- bias gather (scratch col = col-row+15) + mask + online softmax ----
      const bool needmask = (dmax < 63);
#pragma unroll
      for (int nt = 0; nt < 4; nt++) {
        const int col = nt * 16 + ln;
#pragma unroll
        for (int rd = 0; rd < 4; rd++) {
          const int row = lg * 4 + rd;
          const float bias = bf2f(Sc[scb + row * 88 + (col - row + 15)]);
          float s = (s1[nt][rd] + bias) * SCALE;
          if (needmask && col > dmax + row) s = -1e30f;
          s1[nt][rd] = s;
        }
      }
      __builtin_amdgcn_sched_barrier(0);

      float corr[4];
#pragma unroll
      for (int rd = 0; rd < 4; rd++) {
        float mx = fmaxf(fmaxf(s1[0][rd], s1[1][rd]), fmaxf(s1[2][rd], s1[3][rd]));
        mx = fmaxf(mx, __shfl_xor(mx, 1));
        mx = fmaxf(mx, __shfl_xor(mx, 2));
        mx = fmaxf(mx, __shfl_xor(mx, 4));
        mx = fmaxf(mx, __shfl_xor(mx, 8));
        const float mnew = fmaxf(mrun[rd], mx);
        corr[rd] = __expf(mrun[rd] - mnew);
        mrun[rd] = mnew;
      }
#pragma unroll
      for (int nt = 0; nt < 4; nt++)
#pragma unroll
        for (int rd = 0; rd < 4; rd++) s1[nt][rd] = __expf(s1[nt][rd] - mrun[rd]);
#pragma unroll
      for (int rd = 0; rd < 4; rd++) {
        float ls = s1[0][rd] + s1[1][rd] + s1[2][rd] + s1[3][rd];
        ls += __shfl_xor(ls, 1);
        ls += __shfl_xor(ls, 2);
        ls += __shfl_xor(ls, 4);
        ls += __shfl_xor(ls, 8);
        lrun[rd] = lrun[rd] * corr[rd] + ls;
#pragma unroll
        for (int nt = 0; nt < 4; nt++) acc[nt][rd] *= corr[rd];
      }

      // ---- P (hi only) -> wave scratch (aliases S2 region; wave-local order) ----
#pragma unroll
      for (int nt = 0; nt < 4; nt++) {
        const int col = nt * 16 + ln;
#pragma unroll
        for (int rd = 0; rd < 4; rd++) {
          const int row = lg * 4 + rd;
          Sc[scb + row * 72 + col] = f2bf(s1[nt][rd]);
        }
      }
      __builtin_amdgcn_sched_barrier(0);

      // ---- PV: P-hi x V-hi ----
      bf16x8 Ph[2];
#pragma unroll
      for (int ks = 0; ks < 2; ks++)
        Ph[ks] = *(const bf16x8*)&Sc[scb + ln * 72 + (ks * 4 + lg) * 8];
#pragma unroll
      for (int nt = 0; nt < 4; nt++) {
        const int d = nt * 16 + ln;
#pragma unroll
        for (int ks = 0; ks < 2; ks++) {
          const bf16x8 bh = *(const bf16x8*)&Vh[KOFF(d, ks * 4 + lg)];
          acc[nt] = MFMA16(Ph[ks], bh, acc[nt]);
        }
      }
    }
    __syncthreads();   // end of tile kt reads

    if (kt + 1 < nkt) {
      // ---- write staged tile kt+1 (regs -> LDS) ----
      {
        *(uint4*)&Kh[KOFF(ksr, ksc)] = sk;
        const unsigned short p0[4] = {sv0.x, sv0.y, sv0.z, sv0.w};
        const unsigned short p1[4] = {sv1.x, sv1.y, sv1.z, sv1.w};
#pragma unroll
        for (int dd = 0; dd < 4; dd++) {
          const int d = vd0 + dd;
          const int off = (d << 6) + (((vj >> 3) ^ (d & 7)) << 3) + (vj & 7);
          *(unsigned int*)&Vh[off] = (unsigned int)p0[dd] | ((unsigned int)p1[dd] << 16);
        }
        const int m = M0 + 2;    // rel block for tile kt+1
        *(int4*)&Rl[(m & 3) * 4096 + KOFF(rr, rc)] = srl;
      }
      __syncthreads();
      if (kt + 2 < nkt) {
        // ---- issue loads for tile kt+2 (hidden under compute of kt+1) ----
        const int jj = (kt + 2) * 64;
        const size_t krow = ((size_t)(b * SS + jj + ksr)) * QKV3 + 1024 + h * 64 + ksc * 8;
        sk = *(const uint4*)&qkvh[krow];
        const size_t vrow = ((size_t)(b * SS + jj + vj)) * QKV3 + 2048 + h * 64 + vd0;
        sv0 = *(const ushort4*)&qkvh[vrow];
        sv1 = *(const ushort4*)&qkvh[vrow + QKV3];
        const int m = (kt + 2) + M00 + 1;
        const int g = min(max(m * 64 + rr, 0), PP - 1);
        srl = *(const int4*)&relh[(size_t)g * HDIM + rc * 8];
      }
    }
  }

  // ---- epilogue: planar bf16 hi/lo out, [M][1024] ----
#pragma unroll
  for (int rd = 0; rd < 4; rd++) {
    const float inv = 1.f / lrun[rd];
    const size_t orow = ((size_t)(b * SS + i0 + w * 16 + lg * 4 + rd)) * EE + h * 64;
#pragma unroll
    for (int nt = 0; nt < 4; nt++) {
      const float o = acc[nt][rd] * inv;
      const unsigned short hh = f2bf(o);
      abh[orow + nt * 16 + ln] = hh;
      abl[orow + nt * 16 + ln] = f2bf(o - bf2f(hh));
    }
  }
}

// ---------------------------------------------------------------------------
// Launch
// ---------------------------------------------------------------------------
extern "C" void kernel_launch(void* const* d_in, const int* in_sizes, int n_in,
                              void* d_out, int out_size, void* d_ws, size_t ws_size,
                              hipStream_t stream) {
  const float* x   = (const float*)d_in[0];
  const float* Wq  = (const float*)d_in[1];
  const float* bq  = (const float*)d_in[2];
  const float* Wk  = (const float*)d_in[3];
  const float* bk  = (const float*)d_in[4];
  const float* Wv  = (const float*)d_in[5];
  const float* bv  = (const float*)d_in[6];
  const float* Wo  = (const float*)d_in[7];
  const float* bo  = (const float*)d_in[8];
  const float* rel = (const float*)d_in[9];
  float* out = (float*)d_out;

  const int M = BB * SS, K = EE;
  const size_t MB = 1024 * 1024;

  unsigned char* w8 = (unsigned char*)d_ws;
  unsigned short* xh   = (unsigned short*)(w8);             // 8 MB (also abh)
  unsigned short* xl   = (unsigned short*)(w8 + 8 * MB);    // 8 MB (also abl)
  unsigned short* qkvh = (unsigned short*)(w8 + 16 * MB);   // 24 MB
  unsigned short* qkvl = (unsigned short*)(w8 + 40 * MB);   // 24 MB
  unsigned short* wqh  = (unsigned short*)(w8 + 64 * MB);   // 6 MB
  unsigned short* wql  = (unsigned short*)(w8 + 70 * MB);   // 6 MB
  unsigned short* woh  = (unsigned short*)(w8 + 76 * MB);   // 2 MB
  unsigned short* wol  = (unsigned short*)(w8 + 78 * MB);   // 2 MB
  float* bqkv          = (float*)(w8 + 80 * MB);            // 12 KB
  unsigned short* relh = (unsigned short*)(w8 + 80 * MB + 65536);  // 256 KB
  unsigned short* abh = xh;   // x dead after QKV gemm
  unsigned short* abl = xl;

  // conversions
  convert_split_kernel<<<dim3(M * K / 4 / 256), dim3(256), 0, stream>>>(x, xh, xl, M * K / 4);
  convert_wt_kernel<<<dim3(32, 32), dim3(256), 0, stream>>>(Wq, wqh, wql);
  convert_wt_kernel<<<dim3(32, 32), dim3(256), 0, stream>>>(Wk, wqh + (size_t)1024 * EE, wql + (size_t)1024 * EE);
  convert_wt_kernel<<<dim3(32, 32), dim3(256), 0, stream>>>(Wv, wqh + (size_t)2048 * EE, wql + (size_t)2048 * EE);
  convert_wt_kernel<<<dim3(32, 32), dim3(256), 0, stream>>>(Wo, woh, wol);
  bias_concat_kernel<<<dim3(12), dim3(256), 0, stream>>>(bq, bk, bv, bqkv);
  rel_convert_kernel<<<dim3(PP * HDIM / 256), dim3(256), 0, stream>>>(rel, relh);

  // fused QKV projection: planar [M][3072] hi/lo
  gemm_planar_kernel<1, 128><<<dim3(768), dim3(256), 0, stream>>>(
      xh, xl, wqh, wql, bqkv, qkvh, qkvl, nullptr, M, QKV3, K);

  // attention (QBLK=128: 512 blocks x 512 threads, 2 blocks/CU)
  attn_kernel<<<dim3(512), dim3(512), 0, stream>>>(qkvh, qkvl, relh, abh, abl);

  // output projection (BN=64 for 512 blocks = 2/CU)
  gemm_planar_kernel<0, 64><<<dim3(512), dim3(256), 0, stream>>>(
      abh, abl, woh, wol, bo, nullptr, nullptr, out, M, EE, K);
}